// Round 7
// baseline (897.634 us; speedup 1.0000x reference)
//
#include <hip/hip_runtime.h>

#define TT 4
#define BB 16
#define VV 128
#define EE 512
#define HIDC 2048
#define BN_EPS 1e-5f

typedef unsigned int u32;
typedef unsigned long long u64;
typedef unsigned short u16;
typedef unsigned char u8;

// ---------------- all-layer weight transpose: WT[c][o] ----------------
__global__ __launch_bounds__(256) void trans_all(const float* __restrict__ qw,
    const float* __restrict__ f1w, const float* __restrict__ f2w,
    float* __restrict__ wq, float* __restrict__ w1, float* __restrict__ w2)
{
  const int d = blockIdx.z, zz = blockIdx.y;
  const float* src; float* dst; int O, C;
  if (zz < 4)      { src = qw + ((size_t)d * 4 + zz) * EE * EE; dst = wq + ((size_t)d * 4 + zz) * EE * EE; O = EE; C = EE; }
  else if (zz == 4){ src = f1w + (size_t)d * HIDC * EE; dst = w1 + (size_t)d * HIDC * EE; O = HIDC; C = EE; }
  else             { src = f2w + (size_t)d * EE * HIDC; dst = w2 + (size_t)d * EE * HIDC; O = EE; C = HIDC; }
  const int tc_n = C >> 5, to_n = O >> 5;
  const int bx = blockIdx.x;
  if (bx >= tc_n * to_n) return;
  const int tc = bx % tc_n, to = bx / tc_n;
  __shared__ float t[32][33];
  const int tx = threadIdx.x & 31, ty = threadIdx.x >> 5;
#pragma unroll
  for (int k = 0; k < 4; ++k) {
    int o = to * 32 + ty + k * 8, c = tc * 32 + tx;
    t[ty + k * 8][tx] = src[(size_t)o * C + c];
  }
  __syncthreads();
#pragma unroll
  for (int k = 0; k < 4; ++k) {
    int c = tc * 32 + ty + k * 8, o = to * 32 + tx;
    dst[(size_t)c * O + o] = t[tx][ty + k * 8];
  }
}

// ---------------- patch embed + BN + LIF -> h + masks + slot lists ----------------
__global__ __launch_bounds__(256) void pe_lif(const float* __restrict__ x,
    const float* __restrict__ w, const float* __restrict__ bnp,
    float* __restrict__ h, u32* __restrict__ mIn,
    u32* __restrict__ cnt, u16* __restrict__ ids)
{
  const int b = blockIdx.x, eb = blockIdx.y;
  const int tid = threadIdx.x;
  const int chl = tid >> 4, e = eb * 16 + chl;
  const int vs = (tid & 15) * 8;
  __shared__ u8 sB[16][16];
  __shared__ u8 sAct[16];
  const float w0 = w[e * 2], w1 = w[e * 2 + 1];
  const float gg = bnp[e], be = bnp[EE + e], mm = bnp[2 * EE + e], vr = bnp[3 * EE + e];
  const float sc = gg / sqrtf(vr + BN_EPS);
  float vm[8];
#pragma unroll
  for (int k = 0; k < 8; ++k) vm[k] = 0.f;
  for (int t = 0; t < TT; ++t) {
    const int tb = t * BB + b;
    const float* xb = x + (size_t)tb * 2 * VV + vs;
    float4 x0a = *(const float4*)&xb[0],   x0b = *(const float4*)&xb[4];
    float4 x1a = *(const float4*)&xb[VV],  x1b = *(const float4*)&xb[VV + 4];
    float a[8] = {x0a.x, x0a.y, x0a.z, x0a.w, x0b.x, x0b.y, x0b.z, x0b.w};
    float c1[8] = {x1a.x, x1a.y, x1a.z, x1a.w, x1b.x, x1b.y, x1b.z, x1b.w};
    u32 byte = 0;
#pragma unroll
    for (int k = 0; k < 8; ++k) {
      a[k] = (w0 * a[k] + w1 * c1[k] - mm) * sc + be;
      vm[k] += (a[k] - vm[k]) * 0.5f;
      float sp = (vm[k] >= 1.f) ? 1.f : 0.f;
      vm[k] *= (1.f - sp);
      byte |= (sp != 0.f) ? (1u << k) : 0u;
    }
    size_t ho = ((size_t)tb * EE + e) * VV + vs;
    float4 ha = {a[0], a[1], a[2], a[3]}, hb = {a[4], a[5], a[6], a[7]};
    *(float4*)&h[ho] = ha; *(float4*)&h[ho + 4] = hb;
    sB[chl][tid & 15] = (u8)byte;
    __syncthreads();
    if (tid < 16) {
      uint4 mw = *(const uint4*)&sB[tid][0];
      *(uint4*)&mIn[((size_t)tb * EE + eb * 16 + tid) * 4] = mw;
      sAct[tid] = (mw.x | mw.y | mw.z | mw.w) ? 1 : 0;
    }
    __syncthreads();
    if (tid == 0) {
      int c = 0;
      for (int i = 0; i < 16; ++i)
        if (sAct[i]) ids[((size_t)tb * 32 + eb) * 16 + c++] = (u16)(eb * 16 + i);
      cnt[(size_t)tb * 32 + eb] = c;
    }
    __syncthreads();
  }
}

// ---------------- sparse bit-spike GEMM: o-tile 32, thread 4o x 4v, deep unroll ----------------
// grid (B, O/32, nz), 256 thr. Streams WT float4 + mask words from L2, slot lists in/out.
__global__ __launch_bounds__(256) void gemm_fused(
    const u32* __restrict__ InM, const u32* __restrict__ cntI,
    const u16* __restrict__ idsI, int nblkI,
    const float* __restrict__ WT, float* __restrict__ OutPre,
    const float* __restrict__ resid, u32* __restrict__ SpkM,
    u32* __restrict__ cntO, u16* __restrict__ idsO,
    const float* __restrict__ bias, const float* __restrict__ bn1,
    const float* __restrict__ bn2,
    int C, int O, float vth, long wtZ, long spkZ, long bnZ)
{
  const int b = blockIdx.x, ob = blockIdx.y * 32, z = blockIdx.z;
  const int tid = threadIdx.x;
  WT += (long)z * wtZ; SpkM += (long)z * spkZ;
  if (bn1) bn1 += (long)z * bnZ;
  if (bn2) bn2 += (long)z * bnZ;

  __shared__ u16 slist[2048];
  __shared__ u32 scnt[128], soff[128], runb;
  __shared__ u8 sAct[32];

  const int half = tid >> 7;          // o-half (0/1)
  const int o4 = (tid >> 5) & 3;      // 4-o group
  const int vg = tid & 31;            // 4-v nibble group
  const int obase = ob + half * 16 + o4 * 4;
  const int sh4 = (vg & 7) * 4;
  const bool hasb = (bias != nullptr), has1 = (bn1 != nullptr), has2 = (bn2 != nullptr);

  float bs[4], m1c[4], s1c[4], b1c[4], m2c[4], s2c[4], b2c[4];
#pragma unroll
  for (int k = 0; k < 4; ++k) {
    int o = obase + k;
    bs[k] = hasb ? bias[o] : 0.f;
    if (has1) { float g = bn1[o]; b1c[k] = bn1[O + o]; m1c[k] = bn1[2 * O + o];
                s1c[k] = g / sqrtf(bn1[3 * O + o] + BN_EPS); }
    if (has2) { float g = bn2[o]; b2c[k] = bn2[O + o]; m2c[k] = bn2[2 * O + o];
                s2c[k] = g / sqrtf(bn2[3 * O + o] + BN_EPS); }
  }

  float st[4][4] = {};   // LIF membrane per (o-row k, v j)

  for (int t = 0; t < TT; ++t) {
    const int tb = t * BB + b;
    // ---- merge producer slot lists (ascending -> exact fp order) ----
    __syncthreads();
    if (tid < nblkI) scnt[tid] = cntI[(size_t)tb * nblkI + tid];
    __syncthreads();
    if (tid == 0) {
      u32 s = 0;
      for (int i = 0; i < nblkI; ++i) { soff[i] = s; s += scnt[i]; }
      runb = s;
    }
    __syncthreads();
    if (tid < nblkI) {
      u32 o = soff[tid], cn = scnt[tid];
      const u16* src = idsI + ((size_t)tb * nblkI + tid) * 16;
      for (u32 k = 0; k < cn; ++k) slist[o + k] = src[k];
    }
    __syncthreads();
    const int n = (int)runb;

    // ---- K loop: 16 independent FMAs per channel, deep unroll for MLP ----
    float acc[4][4] = {};
    const u32* Mb = InM + (size_t)tb * C * 4 + (vg >> 3);
    const float* Wb = WT + obase;
#pragma unroll 8
    for (int i = 0; i < n; ++i) {
      int c = slist[i];
      u32 mw = Mb[(size_t)c * 4];
      float4 w4 = *(const float4*)&Wb[(size_t)c * O];
      u32 nib = mw >> sh4;
      float f0 = (nib & 1u) ? 1.f : 0.f;
      float f1 = (nib & 2u) ? 1.f : 0.f;
      float f2 = (nib & 4u) ? 1.f : 0.f;
      float f3 = (nib & 8u) ? 1.f : 0.f;
      acc[0][0] += w4.x * f0; acc[0][1] += w4.x * f1; acc[0][2] += w4.x * f2; acc[0][3] += w4.x * f3;
      acc[1][0] += w4.y * f0; acc[1][1] += w4.y * f1; acc[1][2] += w4.y * f2; acc[1][3] += w4.y * f3;
      acc[2][0] += w4.z * f0; acc[2][1] += w4.z * f1; acc[2][2] += w4.z * f2; acc[2][3] += w4.z * f3;
      acc[3][0] += w4.w * f0; acc[3][1] += w4.w * f1; acc[3][2] += w4.w * f2; acc[3][3] += w4.w * f3;
    }

    // ---- epilogue per o-row: bias -> bn1 -> bn2 -> resid -> LIF -> masks ----
#pragma unroll
    for (int k = 0; k < 4; ++k) {
      float a[4] = {acc[k][0], acc[k][1], acc[k][2], acc[k][3]};
      if (hasb) {
#pragma unroll
        for (int j = 0; j < 4; ++j) a[j] += bs[k];
      }
      if (has1) {
#pragma unroll
        for (int j = 0; j < 4; ++j) a[j] = (a[j] - m1c[k]) * s1c[k] + b1c[k];
      }
      if (has2) {
#pragma unroll
        for (int j = 0; j < 4; ++j) a[j] = (a[j] - m2c[k]) * s2c[k] + b2c[k];
      }
      size_t orow = (size_t)tb * O + obase + k;
      if (OutPre) {
        size_t oi = orow * VV + vg * 4;
        float4 r = *(const float4*)&resid[oi];
        a[0] += r.x; a[1] += r.y; a[2] += r.z; a[3] += r.w;
        float4 wr = {a[0], a[1], a[2], a[3]};
        *(float4*)&OutPre[oi] = wr;
      }
      u32 nib = 0;
#pragma unroll
      for (int j = 0; j < 4; ++j) {
        st[k][j] += (a[j] - st[k][j]) * 0.5f;
        float sp = (st[k][j] >= vth) ? 1.f : 0.f;
        st[k][j] *= (1.f - sp);
        nib |= (sp != 0.f) ? (1u << j) : 0u;
      }
      u32 wmask = nib << sh4;
      wmask |= __shfl_xor(wmask, 1);
      wmask |= __shfl_xor(wmask, 2);
      wmask |= __shfl_xor(wmask, 4);
      if ((vg & 7) == 0) SpkM[orow * 4 + (vg >> 3)] = wmask;
      u32 aw = wmask | __shfl_xor(wmask, 8);
      aw |= __shfl_xor(aw, 16);
      if (vg == 0) sAct[half * 16 + o4 * 4 + k] = aw ? 1 : 0;
    }
    if (cntO) {
      __syncthreads();
      if (tid < 2) {
        int slot = blockIdx.y * 2 + tid;
        int c = 0;
        for (int i = 0; i < 16; ++i)
          if (sAct[tid * 16 + i])
            idsO[((size_t)tb * (gridDim.y * 2) + slot) * 16 + c++] = (u16)(ob + tid * 16 + i);
        cntO[(size_t)tb * (gridDim.y * 2) + slot] = c;
      }
    }
  }
}

// ---------------- fused attention: KV=popcount(K&V); O=Q.KV*0.125; LIF(0.5) ----------------
__global__ __launch_bounds__(256) void attn_fused(const u32* __restrict__ Qm,
    const u32* __restrict__ Km, const u32* __restrict__ Vm, u32* __restrict__ Om,
    u32* __restrict__ cntO, u16* __restrict__ idsO)
{
  const int b = blockIdx.x, hh = blockIdx.y, dh = blockIdx.z;
  const int tid = threadIdx.x, lane = tid & 63;
  __shared__ float sQ[64][132];
  __shared__ float sKV[64][36];
  __shared__ u64 sKm[64][2], sQm[64][2], sVm[32][2];
  __shared__ u32 sQnz[64];
  __shared__ u8 sAct[32];
  const int np = lane * 2;
  const int dg = (tid >> 6) * 8;
  float st[8][2] = {};
  for (int t = 0; t < TT; ++t) {
    const int tb = t * BB + b;
    __syncthreads();
    if (tid < 64) {
      uint4 q = *(const uint4*)&Qm[((size_t)tb * EE + hh * 64 + tid) * 4];
      sQm[tid][0] = ((u64)q.y << 32) | q.x; sQm[tid][1] = ((u64)q.w << 32) | q.z;
      sQnz[tid] = q.x | q.y | q.z | q.w;
      uint4 k = *(const uint4*)&Km[((size_t)tb * EE + hh * 64 + tid) * 4];
      sKm[tid][0] = ((u64)k.y << 32) | k.x; sKm[tid][1] = ((u64)k.w << 32) | k.z;
    } else if (tid < 96) {
      int d = tid - 64;
      uint4 v = *(const uint4*)&Vm[((size_t)tb * EE + hh * 64 + dh * 32 + d) * 4];
      sVm[d][0] = ((u64)v.y << 32) | v.x; sVm[d][1] = ((u64)v.w << 32) | v.z;
    }
    __syncthreads();
    {
      int c = tid >> 2, dq = (tid & 3) * 8;
      u64 k0 = sKm[c][0], k1 = sKm[c][1];
#pragma unroll
      for (int i = 0; i < 8; ++i) {
        int d = dq + i;
        int p = __popcll(k0 & sVm[d][0]) + __popcll(k1 & sVm[d][1]);
        sKV[c][d] = (float)p;
      }
    }
    {
      int c = tid >> 2, nq = (tid & 3) * 32;
      u64 qw = sQm[c][nq >> 6] >> (nq & 32);
#pragma unroll
      for (int kk = 0; kk < 8; ++kk) {
        float4 f = {(qw >> (kk * 4)) & 1 ? 1.f : 0.f,
                    (qw >> (kk * 4 + 1)) & 1 ? 1.f : 0.f,
                    (qw >> (kk * 4 + 2)) & 1 ? 1.f : 0.f,
                    (qw >> (kk * 4 + 3)) & 1 ? 1.f : 0.f};
        *(float4*)&sQ[c][nq + kk * 4] = f;
      }
    }
    __syncthreads();
    float acc[8][2] = {};
    for (int c = 0; c < 64; ++c) {
      if (!sQnz[c]) continue;
      float2 q2 = *(const float2*)&sQ[c][np];
      float4 wa = *(const float4*)&sKV[c][dg];
      float4 wb = *(const float4*)&sKV[c][dg + 4];
      float w8[8] = {wa.x, wa.y, wa.z, wa.w, wb.x, wb.y, wb.z, wb.w};
#pragma unroll
      for (int i = 0; i < 8; ++i) { acc[i][0] += w8[i] * q2.x; acc[i][1] += w8[i] * q2.y; }
    }
#pragma unroll
    for (int i = 0; i < 8; ++i) {
      float a0 = acc[i][0] * 0.125f, a1 = acc[i][1] * 0.125f;
      st[i][0] += (a0 - st[i][0]) * 0.5f; st[i][1] += (a1 - st[i][1]) * 0.5f;
      float s0 = (st[i][0] >= 0.5f) ? 1.f : 0.f, s1 = (st[i][1] >= 0.5f) ? 1.f : 0.f;
      st[i][0] *= (1.f - s0); st[i][1] *= (1.f - s1);
      u32 two = ((s0 != 0.f) ? 1u : 0u) | ((s1 != 0.f) ? 2u : 0u);
      u32 wmask = two << ((lane & 15) * 2);
      wmask |= __shfl_xor(wmask, 1);
      wmask |= __shfl_xor(wmask, 2);
      wmask |= __shfl_xor(wmask, 4);
      wmask |= __shfl_xor(wmask, 8);
      if ((lane & 15) == 0)
        Om[((size_t)tb * EE + hh * 64 + dh * 32 + dg + i) * 4 + (lane >> 4)] = wmask;
      u32 aw = wmask | __shfl_xor(wmask, 16);
      aw |= __shfl_xor(aw, 32);
      if (lane == 0) sAct[dg + i] = aw ? 1 : 0;
    }
    __syncthreads();
    if (tid < 2) {
      int slot = hh * 4 + dh * 2 + tid;
      int c = 0;
      for (int i = 0; i < 16; ++i)
        if (sAct[tid * 16 + i])
          idsO[((size_t)tb * 32 + slot) * 16 + c++] = (u16)(hh * 64 + dh * 32 + tid * 16 + i);
      cntO[(size_t)tb * 32 + slot] = c;
    }
  }
}

// ---------------- head: mean over V then LIF over t ----------------
__global__ __launch_bounds__(256) void mean_lif(const float* __restrict__ h,
    float* __restrict__ sh)
{
  int i = blockIdx.x * 256 + threadIdx.x;
  float v = 0.f;
#pragma unroll
  for (int t = 0; t < TT; ++t) {
    const float* p = h + ((size_t)t * BB * EE + i) * VV;
    float s = 0.f;
#pragma unroll
    for (int q = 0; q < VV; q += 4) {
      float4 x = *(const float4*)&p[q];
      s += x.x + x.y + x.z + x.w;
    }
    float hm = s * (1.f / 128.f);
    v += (hm - v) * 0.5f;
    float sp = (v >= 1.f) ? 1.f : 0.f;
    sh[(size_t)t * (BB * EE) + i] = sp;
    v *= (1.f - sp);
  }
}

__global__ __launch_bounds__(256) void head_k2(const float* __restrict__ sh,
    const float* __restrict__ hw, const float* __restrict__ hb,
    float* __restrict__ out)
{
  int g = blockIdx.x * 4 + (threadIdx.x >> 6);
  int lane = threadIdx.x & 63;
  if (g >= BB * 11) return;
  int b = g / 11, n = g % 11;
  float s = 0.f;
#pragma unroll
  for (int t = 0; t < TT; ++t) {
    const float* sp = sh + (size_t)t * (BB * EE) + b * EE;
    const float* wp = hw + n * EE;
    float ss = 0.f;
#pragma unroll
    for (int e = 0; e < EE; e += 64) ss += sp[e + lane] * wp[e + lane];
#pragma unroll
    for (int off = 32; off; off >>= 1) ss += __shfl_down(ss, off);
    if (lane == 0) s += ss;
  }
  if (lane == 0) out[g] = s * 0.25f + hb[n];
}

// ---------------- launch ----------------
extern "C" void kernel_launch(void* const* d_in, const int* in_sizes, int n_in,
                              void* d_out, int out_size, void* d_ws, size_t ws_size,
                              hipStream_t stream) {
  const float* x       = (const float*)d_in[0];
  const float* pe_w    = (const float*)d_in[1];
  const float* pe_bn   = (const float*)d_in[2];
  const float* qkvp_w  = (const float*)d_in[3];
  const float* qkvp_bn = (const float*)d_in[4];
  const float* fc1_w   = (const float*)d_in[5];
  const float* fc1_b   = (const float*)d_in[6];
  const float* fc1_bn  = (const float*)d_in[7];
  const float* fc2_w   = (const float*)d_in[8];
  const float* fc2_b   = (const float*)d_in[9];
  const float* fc2_bn  = (const float*)d_in[10];
  const float* head_w  = (const float*)d_in[11];
  const float* head_b  = (const float*)d_in[12];
  float* out = (float*)d_out;

  const size_t NH = (size_t)TT * BB * EE * VV;       // 4194304
  float* ws = (float*)d_ws;
  float* h   = ws;
  float* wq  = h + NH;
  float* w1  = wq + (size_t)6 * 4 * EE * EE;
  float* w2  = w1 + (size_t)6 * HIDC * EE;
  float* sh  = w2 + (size_t)6 * EE * HIDC;
  u32* mIn  = (u32*)(sh + (size_t)TT * BB * EE);
  u32* mQKV = mIn + (size_t)64 * EE * 4;
  u32* mO   = mQKV + (size_t)3 * 64 * EE * 4;
  u32* mMlp = mO + (size_t)64 * EE * 4;
  u32* mHid = mMlp + (size_t)64 * EE * 4;            // 64*HIDC*4
  u32* cntIn = mHid + (size_t)64 * HIDC * 4;         // [64][32]
  u32* cntO  = cntIn + 64 * 32;
  u32* cntM  = cntO + 64 * 32;
  u32* cntH  = cntM + 64 * 32;                       // [64][128]
  u16* idsIn = (u16*)(cntH + 64 * 128);              // [64][32][16]
  u16* idsO  = idsIn + (size_t)64 * 32 * 16;
  u16* idsM  = idsO + (size_t)64 * 32 * 16;
  u16* idsH  = idsM + (size_t)64 * 32 * 16;          // [64][128][16]

  u32* mQ = mQKV;
  u32* mK = mQKV + (size_t)64 * EE * 4;
  u32* mV = mQKV + (size_t)2 * 64 * EE * 4;

  trans_all<<<dim3(1024, 6, 6), 256, 0, stream>>>(qkvp_w, fc1_w, fc2_w, wq, w1, w2);
  pe_lif<<<dim3(BB, EE / 16), 256, 0, stream>>>(x, pe_w, pe_bn, h, mIn, cntIn, idsIn);

  for (int d = 0; d < 6; ++d) {
    const float* bn1p = qkvp_bn + (size_t)d * 4 * 2 * 4 * EE;
    // qkv (z=3): masks -> Q/K/V masks
    gemm_fused<<<dim3(BB, EE / 32, 3), 256, 0, stream>>>(mIn, cntIn, idsIn, 32,
        wq + (size_t)d * 4 * EE * EE, nullptr, nullptr, mQ, nullptr, nullptr,
        nullptr, bn1p, bn1p + 4 * EE, EE, EE, 1.f,
        (long)EE * EE, (long)64 * EE * 4, (long)2 * 4 * EE);
    attn_fused<<<dim3(BB, 8, 2), 256, 0, stream>>>(mQ, mK, mV, mO, cntO, idsO);
    // proj: + resid -> h; LIF(1) -> mMlp + lists
    gemm_fused<<<dim3(BB, EE / 32, 1), 256, 0, stream>>>(mO, cntO, idsO, 32,
        wq + ((size_t)d * 4 + 3) * EE * EE, h, h, mMlp, cntM, idsM,
        nullptr, bn1p + 3 * (2 * 4 * EE), bn1p + 3 * (2 * 4 * EE) + 4 * EE,
        EE, EE, 1.f, 0, 0, 0);
    // fc1: bias+bn; LIF(1) -> mHid + lists
    gemm_fused<<<dim3(BB, HIDC / 32, 1), 256, 0, stream>>>(mMlp, cntM, idsM, 32,
        w1 + (size_t)d * HIDC * EE, nullptr, nullptr, mHid, cntH, idsH,
        fc1_b + (size_t)d * HIDC, fc1_bn + (size_t)d * 4 * HIDC, nullptr,
        EE, HIDC, 1.f, 0, 0, 0);
    // fc2: bias+bn + resid -> h; LIF(1) -> mIn + lists (next layer input)
    gemm_fused<<<dim3(BB, EE / 32, 1), 256, 0, stream>>>(mHid, cntH, idsH, 128,
        w2 + (size_t)d * EE * HIDC, h, h, mIn, cntIn, idsIn,
        fc2_b + (size_t)d * EE, fc2_bn + (size_t)d * 4 * EE, nullptr,
        HIDC, EE, 1.f, 0, 0, 0);
  }

  mean_lif<<<32, 256, 0, stream>>>(h, sh);
  head_k2<<<44, 256, 0, stream>>>(sh, head_w, head_b, out);
}

// Round 8
// 833.684 us; speedup vs baseline: 1.0767x; 1.0767x over previous
//
#include <hip/hip_runtime.h>

#define TT 4
#define BB 16
#define VV 128
#define EE 512
#define HIDC 2048
#define BN_EPS 1e-5f

typedef unsigned int u32;
typedef unsigned long long u64;
typedef unsigned short u16;
typedef unsigned char u8;

// ---------------- all-layer weight transpose: WT[c][o] ----------------
__global__ __launch_bounds__(256) void trans_all(const float* __restrict__ qw,
    const float* __restrict__ f1w, const float* __restrict__ f2w,
    float* __restrict__ wq, float* __restrict__ w1, float* __restrict__ w2)
{
  const int d = blockIdx.z, zz = blockIdx.y;
  const float* src; float* dst; int O, C;
  if (zz < 4)      { src = qw + ((size_t)d * 4 + zz) * EE * EE; dst = wq + ((size_t)d * 4 + zz) * EE * EE; O = EE; C = EE; }
  else if (zz == 4){ src = f1w + (size_t)d * HIDC * EE; dst = w1 + (size_t)d * HIDC * EE; O = HIDC; C = EE; }
  else             { src = f2w + (size_t)d * EE * HIDC; dst = w2 + (size_t)d * EE * HIDC; O = EE; C = HIDC; }
  const int tc_n = C >> 5, to_n = O >> 5;
  const int bx = blockIdx.x;
  if (bx >= tc_n * to_n) return;
  const int tc = bx % tc_n, to = bx / tc_n;
  __shared__ float t[32][33];
  const int tx = threadIdx.x & 31, ty = threadIdx.x >> 5;
#pragma unroll
  for (int k = 0; k < 4; ++k) {
    int o = to * 32 + ty + k * 8, c = tc * 32 + tx;
    t[ty + k * 8][tx] = src[(size_t)o * C + c];
  }
  __syncthreads();
#pragma unroll
  for (int k = 0; k < 4; ++k) {
    int c = tc * 32 + ty + k * 8, o = to * 32 + tx;
    dst[(size_t)c * O + o] = t[tx][ty + k * 8];
  }
}

// ---------------- patch embed + BN + LIF -> h + masks + slot lists ----------------
__global__ __launch_bounds__(256) void pe_lif(const float* __restrict__ x,
    const float* __restrict__ w, const float* __restrict__ bnp,
    float* __restrict__ h, u32* __restrict__ mIn,
    u32* __restrict__ cnt, u16* __restrict__ ids)
{
  const int b = blockIdx.x, eb = blockIdx.y;
  const int tid = threadIdx.x;
  const int chl = tid >> 4, e = eb * 16 + chl;
  const int vs = (tid & 15) * 8;
  __shared__ u8 sB[16][16];
  __shared__ u8 sAct[16];
  const float w0 = w[e * 2], w1 = w[e * 2 + 1];
  const float gg = bnp[e], be = bnp[EE + e], mm = bnp[2 * EE + e], vr = bnp[3 * EE + e];
  const float sc = gg / sqrtf(vr + BN_EPS);
  float vm[8];
#pragma unroll
  for (int k = 0; k < 8; ++k) vm[k] = 0.f;
  for (int t = 0; t < TT; ++t) {
    const int tb = t * BB + b;
    const float* xb = x + (size_t)tb * 2 * VV + vs;
    float4 x0a = *(const float4*)&xb[0],   x0b = *(const float4*)&xb[4];
    float4 x1a = *(const float4*)&xb[VV],  x1b = *(const float4*)&xb[VV + 4];
    float a[8] = {x0a.x, x0a.y, x0a.z, x0a.w, x0b.x, x0b.y, x0b.z, x0b.w};
    float c1[8] = {x1a.x, x1a.y, x1a.z, x1a.w, x1b.x, x1b.y, x1b.z, x1b.w};
    u32 byte = 0;
#pragma unroll
    for (int k = 0; k < 8; ++k) {
      a[k] = (w0 * a[k] + w1 * c1[k] - mm) * sc + be;
      vm[k] += (a[k] - vm[k]) * 0.5f;
      float sp = (vm[k] >= 1.f) ? 1.f : 0.f;
      vm[k] *= (1.f - sp);
      byte |= (sp != 0.f) ? (1u << k) : 0u;
    }
    size_t ho = ((size_t)tb * EE + e) * VV + vs;
    float4 ha = {a[0], a[1], a[2], a[3]}, hb = {a[4], a[5], a[6], a[7]};
    *(float4*)&h[ho] = ha; *(float4*)&h[ho + 4] = hb;
    sB[chl][tid & 15] = (u8)byte;
    __syncthreads();
    if (tid < 16) {
      uint4 mw = *(const uint4*)&sB[tid][0];
      *(uint4*)&mIn[((size_t)tb * EE + eb * 16 + tid) * 4] = mw;
      sAct[tid] = (mw.x | mw.y | mw.z | mw.w) ? 1 : 0;
    }
    __syncthreads();
    if (tid == 0) {
      int c = 0;
      for (int i = 0; i < 16; ++i)
        if (sAct[i]) ids[((size_t)tb * 32 + eb) * 16 + c++] = (u16)(eb * 16 + i);
      cnt[(size_t)tb * 32 + eb] = c;
    }
    __syncthreads();
  }
}

// ---------------- sparse bit-spike GEMM: LDS-staged 64ch tiles, slot lists ----------------
// grid (B, O/32, nz), 256 thr. Thread: 4o x 4v. Merge via wave prefix-scan.
__global__ __launch_bounds__(256) void gemm_fused(
    const u32* __restrict__ InM, const u32* __restrict__ cntI,
    const u16* __restrict__ idsI, int nblkI,
    const float* __restrict__ WT, float* __restrict__ OutPre,
    const float* __restrict__ resid, u32* __restrict__ SpkM,
    u32* __restrict__ cntO, u16* __restrict__ idsO,
    const float* __restrict__ bias, const float* __restrict__ bn1,
    const float* __restrict__ bn2,
    int C, int O, float vth, long wtZ, long spkZ, long bnZ)
{
  const int b = blockIdx.x, ob = blockIdx.y * 32, z = blockIdx.z;
  const int tid = threadIdx.x, lane = tid & 63, wv = tid >> 6;
  WT += (long)z * wtZ; SpkM += (long)z * spkZ;
  if (bn1) bn1 += (long)z * bnZ;
  if (bn2) bn2 += (long)z * bnZ;

  __shared__ u16 slist[2048];
  __shared__ float sW[64][32];
  __shared__ u32 sM[64][4];
  __shared__ u32 sWS[2];
  __shared__ u32 runbS;
  __shared__ u8 sAct[32];

  const int og = (tid >> 5) * 4;     // 8 groups x 4 o
  const int vg = tid & 31;           // 4 v each
  const int wword = vg >> 3;
  const int sh4 = (vg & 7) * 4;
  const bool hasb = (bias != nullptr), has1 = (bn1 != nullptr), has2 = (bn2 != nullptr);

  float bs[4], m1c[4], s1c[4], b1c[4], m2c[4], s2c[4], b2c[4];
#pragma unroll
  for (int k = 0; k < 4; ++k) {
    int o = ob + og + k;
    bs[k] = hasb ? bias[o] : 0.f;
    if (has1) { float g = bn1[o]; b1c[k] = bn1[O + o]; m1c[k] = bn1[2 * O + o];
                s1c[k] = g / sqrtf(bn1[3 * O + o] + BN_EPS); }
    if (has2) { float g = bn2[o]; b2c[k] = bn2[O + o]; m2c[k] = bn2[2 * O + o];
                s2c[k] = g / sqrtf(bn2[3 * O + o] + BN_EPS); }
  }

  float st[4][4] = {};   // LIF membrane per (o-row, v)
  const float* WTb = WT + ob;

  for (int t = 0; t < TT; ++t) {
    const int tb = t * BB + b;
    const u32* Mrow = InM + (size_t)tb * C * 4;

    // ---- merge producer slot lists via wave prefix scan (ascending order) ----
    __syncthreads();                       // protect slist/sAct reuse
    u32 c = 0;
    if (tid < nblkI) c = cntI[(size_t)tb * nblkI + tid];
    u32 xs = c;
#pragma unroll
    for (int off = 1; off < 64; off <<= 1) {
      u32 y = __shfl_up(xs, off);
      if (lane >= off) xs += y;
    }
    if (lane == 63 && wv < 2) sWS[wv] = xs;
    __syncthreads();
    if (tid < nblkI && c) {
      u32 o = ((wv == 1) ? sWS[0] : 0u) + xs - c;
      const u16* src = idsI + ((size_t)tb * nblkI + tid) * 16;
      for (u32 k = 0; k < c; ++k) slist[o + k] = src[k];
    }
    if (tid == 0) runbS = sWS[0] + ((nblkI > 64) ? sWS[1] : 0u);
    __syncthreads();
    const int n = (int)runbS;

    // ---- K loop: 64-channel LDS-staged tiles ----
    float acc[4][4] = {};
    for (int a0 = 0; a0 < n; a0 += 64) {
      int m = n - a0; if (m > 64) m = 64;
      if (a0) __syncthreads();             // protect sW/sM reuse
      {
        int cc = tid >> 3, q = (tid & 7) * 4;
        if (cc < m) { int ch = slist[a0 + cc];
          *(float4*)&sW[cc][q] = *(const float4*)&WTb[(size_t)ch * O + q]; }
        int cc2 = cc + 32;
        if (cc2 < m) { int ch = slist[a0 + cc2];
          *(float4*)&sW[cc2][q] = *(const float4*)&WTb[(size_t)ch * O + q]; }
        int cm = tid >> 2, qm = tid & 3;
        if (cm < m) sM[cm][qm] = Mrow[(size_t)slist[a0 + cm] * 4 + qm];
      }
      __syncthreads();
#pragma unroll 4
      for (int i = 0; i < m; ++i) {
        u32 nib = sM[i][wword] >> sh4;
        float4 w4 = *(const float4*)&sW[i][og];
        float f0 = (float)(nib & 1u);
        float f1 = (float)((nib >> 1) & 1u);
        float f2 = (float)((nib >> 2) & 1u);
        float f3 = (float)((nib >> 3) & 1u);
        acc[0][0] += w4.x * f0; acc[0][1] += w4.x * f1; acc[0][2] += w4.x * f2; acc[0][3] += w4.x * f3;
        acc[1][0] += w4.y * f0; acc[1][1] += w4.y * f1; acc[1][2] += w4.y * f2; acc[1][3] += w4.y * f3;
        acc[2][0] += w4.z * f0; acc[2][1] += w4.z * f1; acc[2][2] += w4.z * f2; acc[2][3] += w4.z * f3;
        acc[3][0] += w4.w * f0; acc[3][1] += w4.w * f1; acc[3][2] += w4.w * f2; acc[3][3] += w4.w * f3;
      }
    }

    // ---- epilogue: bias -> bn1 -> bn2 -> resid -> LIF -> masks + activity ----
#pragma unroll
    for (int k = 0; k < 4; ++k) {
      float a[4] = {acc[k][0], acc[k][1], acc[k][2], acc[k][3]};
      if (hasb) {
#pragma unroll
        for (int j = 0; j < 4; ++j) a[j] += bs[k];
      }
      if (has1) {
#pragma unroll
        for (int j = 0; j < 4; ++j) a[j] = (a[j] - m1c[k]) * s1c[k] + b1c[k];
      }
      if (has2) {
#pragma unroll
        for (int j = 0; j < 4; ++j) a[j] = (a[j] - m2c[k]) * s2c[k] + b2c[k];
      }
      size_t orow = (size_t)tb * O + ob + og + k;
      if (OutPre) {
        size_t oi = orow * VV + vg * 4;
        float4 r = *(const float4*)&resid[oi];
        a[0] += r.x; a[1] += r.y; a[2] += r.z; a[3] += r.w;
        float4 wr = {a[0], a[1], a[2], a[3]};
        *(float4*)&OutPre[oi] = wr;
      }
      u32 nib = 0;
#pragma unroll
      for (int j = 0; j < 4; ++j) {
        st[k][j] += (a[j] - st[k][j]) * 0.5f;
        float sp = (st[k][j] >= vth) ? 1.f : 0.f;
        st[k][j] *= (1.f - sp);
        nib |= (sp != 0.f) ? (1u << j) : 0u;
      }
      u32 wmask = nib << sh4;
      wmask |= __shfl_xor(wmask, 1);
      wmask |= __shfl_xor(wmask, 2);
      wmask |= __shfl_xor(wmask, 4);
      if ((vg & 7) == 0) SpkM[orow * 4 + wword] = wmask;
      u32 aw = wmask | __shfl_xor(wmask, 8);
      aw |= __shfl_xor(aw, 16);
      if (vg == 0) sAct[og + k] = aw ? 1 : 0;
    }
    if (cntO) {
      __syncthreads();
      if (tid < 2) {
        int slot = blockIdx.y * 2 + tid;
        int cc = 0;
        for (int i = 0; i < 16; ++i)
          if (sAct[tid * 16 + i])
            idsO[((size_t)tb * (gridDim.y * 2) + slot) * 16 + cc++] = (u16)(ob + tid * 16 + i);
        cntO[(size_t)tb * (gridDim.y * 2) + slot] = cc;
      }
    }
  }
}

// ---------------- fused attention: KV=popcount(K&V); O=Q.KV*0.125; LIF(0.5) ----------------
__global__ __launch_bounds__(256) void attn_fused(const u32* __restrict__ Qm,
    const u32* __restrict__ Km, const u32* __restrict__ Vm, u32* __restrict__ Om,
    u32* __restrict__ cntO, u16* __restrict__ idsO)
{
  const int b = blockIdx.x, hh = blockIdx.y, dh = blockIdx.z;
  const int tid = threadIdx.x, lane = tid & 63;
  __shared__ float sQ[64][132];
  __shared__ float sKV[64][36];
  __shared__ u64 sKm[64][2], sQm[64][2], sVm[32][2];
  __shared__ u32 sQnz[64];
  __shared__ u8 sAct[32];
  const int np = lane * 2;
  const int dg = (tid >> 6) * 8;
  float st[8][2] = {};
  for (int t = 0; t < TT; ++t) {
    const int tb = t * BB + b;
    __syncthreads();
    if (tid < 64) {
      uint4 q = *(const uint4*)&Qm[((size_t)tb * EE + hh * 64 + tid) * 4];
      sQm[tid][0] = ((u64)q.y << 32) | q.x; sQm[tid][1] = ((u64)q.w << 32) | q.z;
      sQnz[tid] = q.x | q.y | q.z | q.w;
      uint4 k = *(const uint4*)&Km[((size_t)tb * EE + hh * 64 + tid) * 4];
      sKm[tid][0] = ((u64)k.y << 32) | k.x; sKm[tid][1] = ((u64)k.w << 32) | k.z;
    } else if (tid < 96) {
      int d = tid - 64;
      uint4 v = *(const uint4*)&Vm[((size_t)tb * EE + hh * 64 + dh * 32 + d) * 4];
      sVm[d][0] = ((u64)v.y << 32) | v.x; sVm[d][1] = ((u64)v.w << 32) | v.z;
    }
    __syncthreads();
    {
      int c = tid >> 2, dq = (tid & 3) * 8;
      u64 k0 = sKm[c][0], k1 = sKm[c][1];
#pragma unroll
      for (int i = 0; i < 8; ++i) {
        int d = dq + i;
        int p = __popcll(k0 & sVm[d][0]) + __popcll(k1 & sVm[d][1]);
        sKV[c][d] = (float)p;
      }
    }
    {
      int c = tid >> 2, nq = (tid & 3) * 32;
      u64 qw = sQm[c][nq >> 6] >> (nq & 32);
#pragma unroll
      for (int kk = 0; kk < 8; ++kk) {
        float4 f = {(qw >> (kk * 4)) & 1 ? 1.f : 0.f,
                    (qw >> (kk * 4 + 1)) & 1 ? 1.f : 0.f,
                    (qw >> (kk * 4 + 2)) & 1 ? 1.f : 0.f,
                    (qw >> (kk * 4 + 3)) & 1 ? 1.f : 0.f};
        *(float4*)&sQ[c][nq + kk * 4] = f;
      }
    }
    __syncthreads();
    float acc[8][2] = {};
    for (int c = 0; c < 64; ++c) {
      if (!sQnz[c]) continue;
      float2 q2 = *(const float2*)&sQ[c][np];
      float4 wa = *(const float4*)&sKV[c][dg];
      float4 wb = *(const float4*)&sKV[c][dg + 4];
      float w8[8] = {wa.x, wa.y, wa.z, wa.w, wb.x, wb.y, wb.z, wb.w};
#pragma unroll
      for (int i = 0; i < 8; ++i) { acc[i][0] += w8[i] * q2.x; acc[i][1] += w8[i] * q2.y; }
    }
#pragma unroll
    for (int i = 0; i < 8; ++i) {
      float a0 = acc[i][0] * 0.125f, a1 = acc[i][1] * 0.125f;
      st[i][0] += (a0 - st[i][0]) * 0.5f; st[i][1] += (a1 - st[i][1]) * 0.5f;
      float s0 = (st[i][0] >= 0.5f) ? 1.f : 0.f, s1 = (st[i][1] >= 0.5f) ? 1.f : 0.f;
      st[i][0] *= (1.f - s0); st[i][1] *= (1.f - s1);
      u32 two = ((s0 != 0.f) ? 1u : 0u) | ((s1 != 0.f) ? 2u : 0u);
      u32 wmask = two << ((lane & 15) * 2);
      wmask |= __shfl_xor(wmask, 1);
      wmask |= __shfl_xor(wmask, 2);
      wmask |= __shfl_xor(wmask, 4);
      wmask |= __shfl_xor(wmask, 8);
      if ((lane & 15) == 0)
        Om[((size_t)tb * EE + hh * 64 + dh * 32 + dg + i) * 4 + (lane >> 4)] = wmask;
      u32 aw = wmask | __shfl_xor(wmask, 16);
      aw |= __shfl_xor(aw, 32);
      if (lane == 0) sAct[dg + i] = aw ? 1 : 0;
    }
    __syncthreads();
    if (tid < 2) {
      int slot = hh * 4 + dh * 2 + tid;
      int c = 0;
      for (int i = 0; i < 16; ++i)
        if (sAct[tid * 16 + i])
          idsO[((size_t)tb * 32 + slot) * 16 + c++] = (u16)(hh * 64 + dh * 32 + tid * 16 + i);
      cntO[(size_t)tb * 32 + slot] = c;
    }
  }
}

// ---------------- head: mean over V then LIF over t ----------------
__global__ __launch_bounds__(256) void mean_lif(const float* __restrict__ h,
    float* __restrict__ sh)
{
  int i = blockIdx.x * 256 + threadIdx.x;
  float v = 0.f;
#pragma unroll
  for (int t = 0; t < TT; ++t) {
    const float* p = h + ((size_t)t * BB * EE + i) * VV;
    float s = 0.f;
#pragma unroll
    for (int q = 0; q < VV; q += 4) {
      float4 x = *(const float4*)&p[q];
      s += x.x + x.y + x.z + x.w;
    }
    float hm = s * (1.f / 128.f);
    v += (hm - v) * 0.5f;
    float sp = (v >= 1.f) ? 1.f : 0.f;
    sh[(size_t)t * (BB * EE) + i] = sp;
    v *= (1.f - sp);
  }
}

__global__ __launch_bounds__(256) void head_k2(const float* __restrict__ sh,
    const float* __restrict__ hw, const float* __restrict__ hb,
    float* __restrict__ out)
{
  int g = blockIdx.x * 4 + (threadIdx.x >> 6);
  int lane = threadIdx.x & 63;
  if (g >= BB * 11) return;
  int b = g / 11, n = g % 11;
  float s = 0.f;
#pragma unroll
  for (int t = 0; t < TT; ++t) {
    const float* sp = sh + (size_t)t * (BB * EE) + b * EE;
    const float* wp = hw + n * EE;
    float ss = 0.f;
#pragma unroll
    for (int e = 0; e < EE; e += 64) ss += sp[e + lane] * wp[e + lane];
#pragma unroll
    for (int off = 32; off; off >>= 1) ss += __shfl_down(ss, off);
    if (lane == 0) s += ss;
  }
  if (lane == 0) out[g] = s * 0.25f + hb[n];
}

// ---------------- launch ----------------
extern "C" void kernel_launch(void* const* d_in, const int* in_sizes, int n_in,
                              void* d_out, int out_size, void* d_ws, size_t ws_size,
                              hipStream_t stream) {
  const float* x       = (const float*)d_in[0];
  const float* pe_w    = (const float*)d_in[1];
  const float* pe_bn   = (const float*)d_in[2];
  const float* qkvp_w  = (const float*)d_in[3];
  const float* qkvp_bn = (const float*)d_in[4];
  const float* fc1_w   = (const float*)d_in[5];
  const float* fc1_b   = (const float*)d_in[6];
  const float* fc1_bn  = (const float*)d_in[7];
  const float* fc2_w   = (const float*)d_in[8];
  const float* fc2_b   = (const float*)d_in[9];
  const float* fc2_bn  = (const float*)d_in[10];
  const float* head_w  = (const float*)d_in[11];
  const float* head_b  = (const float*)d_in[12];
  float* out = (float*)d_out;

  const size_t NH = (size_t)TT * BB * EE * VV;       // 4194304
  float* ws = (float*)d_ws;
  float* h   = ws;
  float* wq  = h + NH;
  float* w1  = wq + (size_t)6 * 4 * EE * EE;
  float* w2  = w1 + (size_t)6 * HIDC * EE;
  float* sh  = w2 + (size_t)6 * EE * HIDC;
  u32* mIn  = (u32*)(sh + (size_t)TT * BB * EE);
  u32* mQKV = mIn + (size_t)64 * EE * 4;
  u32* mO   = mQKV + (size_t)3 * 64 * EE * 4;
  u32* mMlp = mO + (size_t)64 * EE * 4;
  u32* mHid = mMlp + (size_t)64 * EE * 4;            // 64*HIDC*4
  u32* cntIn = mHid + (size_t)64 * HIDC * 4;         // [64][32]
  u32* cntO  = cntIn + 64 * 32;
  u32* cntM  = cntO + 64 * 32;
  u32* cntH  = cntM + 64 * 32;                       // [64][128]
  u16* idsIn = (u16*)(cntH + 64 * 128);              // [64][32][16]
  u16* idsO  = idsIn + (size_t)64 * 32 * 16;
  u16* idsM  = idsO + (size_t)64 * 32 * 16;
  u16* idsH  = idsM + (size_t)64 * 32 * 16;          // [64][128][16]

  u32* mQ = mQKV;
  u32* mK = mQKV + (size_t)64 * EE * 4;
  u32* mV = mQKV + (size_t)2 * 64 * EE * 4;

  trans_all<<<dim3(1024, 6, 6), 256, 0, stream>>>(qkvp_w, fc1_w, fc2_w, wq, w1, w2);
  pe_lif<<<dim3(BB, EE / 16), 256, 0, stream>>>(x, pe_w, pe_bn, h, mIn, cntIn, idsIn);

  for (int d = 0; d < 6; ++d) {
    const float* bn1p = qkvp_bn + (size_t)d * 4 * 2 * 4 * EE;
    // qkv (z=3): masks -> Q/K/V masks
    gemm_fused<<<dim3(BB, EE / 32, 3), 256, 0, stream>>>(mIn, cntIn, idsIn, 32,
        wq + (size_t)d * 4 * EE * EE, nullptr, nullptr, mQ, nullptr, nullptr,
        nullptr, bn1p, bn1p + 4 * EE, EE, EE, 1.f,
        (long)EE * EE, (long)64 * EE * 4, (long)2 * 4 * EE);
    attn_fused<<<dim3(BB, 8, 2), 256, 0, stream>>>(mQ, mK, mV, mO, cntO, idsO);
    // proj: + resid -> h; LIF(1) -> mMlp + lists
    gemm_fused<<<dim3(BB, EE / 32, 1), 256, 0, stream>>>(mO, cntO, idsO, 32,
        wq + ((size_t)d * 4 + 3) * EE * EE, h, h, mMlp, cntM, idsM,
        nullptr, bn1p + 3 * (2 * 4 * EE), bn1p + 3 * (2 * 4 * EE) + 4 * EE,
        EE, EE, 1.f, 0, 0, 0);
    // fc1: bias+bn; LIF(1) -> mHid + lists
    gemm_fused<<<dim3(BB, HIDC / 32, 1), 256, 0, stream>>>(mMlp, cntM, idsM, 32,
        w1 + (size_t)d * HIDC * EE, nullptr, nullptr, mHid, cntH, idsH,
        fc1_b + (size_t)d * HIDC, fc1_bn + (size_t)d * 4 * HIDC, nullptr,
        EE, HIDC, 1.f, 0, 0, 0);
    // fc2: bias+bn + resid -> h; LIF(1) -> mIn + lists (next layer input)
    gemm_fused<<<dim3(BB, EE / 32, 1), 256, 0, stream>>>(mHid, cntH, idsH, 128,
        w2 + (size_t)d * EE * HIDC, h, h, mIn, cntIn, idsIn,
        fc2_b + (size_t)d * EE, fc2_bn + (size_t)d * 4 * EE, nullptr,
        HIDC, EE, 1.f, 0, 0, 0);
  }

  mean_lif<<<32, 256, 0, stream>>>(h, sh);
  head_k2<<<44, 256, 0, stream>>>(sh, head_w, head_b, out);
}

// Round 9
// 768.268 us; speedup vs baseline: 1.1684x; 1.0851x over previous
//
#include <hip/hip_runtime.h>

#define TT 4
#define BB 16
#define VV 128
#define EE 512
#define HIDC 2048
#define BN_EPS 1e-5f

typedef unsigned int u32;
typedef unsigned long long u64;
typedef unsigned short u16;
typedef unsigned char u8;

// ---------------- all-layer weight transpose: WT[c][o] ----------------
__global__ __launch_bounds__(256) void trans_all(const float* __restrict__ qw,
    const float* __restrict__ f1w, const float* __restrict__ f2w,
    float* __restrict__ wq, float* __restrict__ w1, float* __restrict__ w2)
{
  const int d = blockIdx.z, zz = blockIdx.y;
  const float* src; float* dst; int O, C;
  if (zz < 4)      { src = qw + ((size_t)d * 4 + zz) * EE * EE; dst = wq + ((size_t)d * 4 + zz) * EE * EE; O = EE; C = EE; }
  else if (zz == 4){ src = f1w + (size_t)d * HIDC * EE; dst = w1 + (size_t)d * HIDC * EE; O = HIDC; C = EE; }
  else             { src = f2w + (size_t)d * EE * HIDC; dst = w2 + (size_t)d * EE * HIDC; O = EE; C = HIDC; }
  const int tc_n = C >> 5, to_n = O >> 5;
  const int bx = blockIdx.x;
  if (bx >= tc_n * to_n) return;
  const int tc = bx % tc_n, to = bx / tc_n;
  __shared__ float t[32][33];
  const int tx = threadIdx.x & 31, ty = threadIdx.x >> 5;
#pragma unroll
  for (int k = 0; k < 4; ++k) {
    int o = to * 32 + ty + k * 8, c = tc * 32 + tx;
    t[ty + k * 8][tx] = src[(size_t)o * C + c];
  }
  __syncthreads();
#pragma unroll
  for (int k = 0; k < 4; ++k) {
    int c = tc * 32 + ty + k * 8, o = to * 32 + tx;
    dst[(size_t)c * O + o] = t[tx][ty + k * 8];
  }
}

// ---------------- patch embed + BN + LIF -> h + masks + slot lists ----------------
__global__ __launch_bounds__(256) void pe_lif(const float* __restrict__ x,
    const float* __restrict__ w, const float* __restrict__ bnp,
    float* __restrict__ h, u32* __restrict__ mIn,
    u32* __restrict__ cnt, u16* __restrict__ ids)
{
  const int b = blockIdx.x, eb = blockIdx.y;
  const int tid = threadIdx.x;
  const int chl = tid >> 4, e = eb * 16 + chl;
  const int vs = (tid & 15) * 8;
  __shared__ u8 sB[16][16];
  __shared__ u8 sAct[16];
  const float w0 = w[e * 2], w1 = w[e * 2 + 1];
  const float gg = bnp[e], be = bnp[EE + e], mm = bnp[2 * EE + e], vr = bnp[3 * EE + e];
  const float sc = gg / sqrtf(vr + BN_EPS);
  float vm[8];
#pragma unroll
  for (int k = 0; k < 8; ++k) vm[k] = 0.f;
  for (int t = 0; t < TT; ++t) {
    const int tb = t * BB + b;
    const float* xb = x + (size_t)tb * 2 * VV + vs;
    float4 x0a = *(const float4*)&xb[0],   x0b = *(const float4*)&xb[4];
    float4 x1a = *(const float4*)&xb[VV],  x1b = *(const float4*)&xb[VV + 4];
    float a[8] = {x0a.x, x0a.y, x0a.z, x0a.w, x0b.x, x0b.y, x0b.z, x0b.w};
    float c1[8] = {x1a.x, x1a.y, x1a.z, x1a.w, x1b.x, x1b.y, x1b.z, x1b.w};
    u32 byte = 0;
#pragma unroll
    for (int k = 0; k < 8; ++k) {
      a[k] = (w0 * a[k] + w1 * c1[k] - mm) * sc + be;
      vm[k] += (a[k] - vm[k]) * 0.5f;
      float sp = (vm[k] >= 1.f) ? 1.f : 0.f;
      vm[k] *= (1.f - sp);
      byte |= (sp != 0.f) ? (1u << k) : 0u;
    }
    size_t ho = ((size_t)tb * EE + e) * VV + vs;
    float4 ha = {a[0], a[1], a[2], a[3]}, hb = {a[4], a[5], a[6], a[7]};
    *(float4*)&h[ho] = ha; *(float4*)&h[ho + 4] = hb;
    sB[chl][tid & 15] = (u8)byte;
    __syncthreads();
    if (tid < 16) {
      uint4 mw = *(const uint4*)&sB[tid][0];
      *(uint4*)&mIn[((size_t)tb * EE + eb * 16 + tid) * 4] = mw;
      sAct[tid] = (mw.x | mw.y | mw.z | mw.w) ? 1 : 0;
    }
    __syncthreads();
    if (tid == 0) {
      int c = 0;
      for (int i = 0; i < 16; ++i)
        if (sAct[i]) ids[((size_t)tb * 32 + eb) * 16 + c++] = (u16)(eb * 16 + i);
      cnt[(size_t)tb * 32 + eb] = c;
    }
    __syncthreads();
  }
}

// ---------------- sparse bit-spike GEMM: o-tile 16, 64ch LDS stages, slot lists ----------------
// grid (B, O/16, nz), 256 thr. Thread: 2o x 4v. Merge via wave prefix-scan.
__global__ __launch_bounds__(256) void gemm_fused(
    const u32* __restrict__ InM, const u32* __restrict__ cntI,
    const u16* __restrict__ idsI, int nblkI,
    const float* __restrict__ WT, float* __restrict__ OutPre,
    const float* __restrict__ resid, u32* __restrict__ SpkM,
    u32* __restrict__ cntO, u16* __restrict__ idsO,
    const float* __restrict__ bias, const float* __restrict__ bn1,
    const float* __restrict__ bn2,
    int C, int O, float vth, long wtZ, long spkZ, long bnZ)
{
  const int b = blockIdx.x, ob = blockIdx.y * 16, z = blockIdx.z;
  const int tid = threadIdx.x, lane = tid & 63, wv = tid >> 6;
  WT += (long)z * wtZ; SpkM += (long)z * spkZ;
  if (bn1) bn1 += (long)z * bnZ;
  if (bn2) bn2 += (long)z * bnZ;

  __shared__ u16 slist[2048];
  __shared__ float sW[64][16];
  __shared__ u32 sM[64][4];
  __shared__ u32 sWS[2];
  __shared__ u32 runbS;
  __shared__ u8 sAct[16];

  const int og = (tid >> 5) * 2;     // 8 groups x 2 o
  const int vg = tid & 31;           // 4 v each
  const int wword = vg >> 3;
  const int sh4 = (vg & 7) * 4;
  const bool hasb = (bias != nullptr), has1 = (bn1 != nullptr), has2 = (bn2 != nullptr);

  float bs[2], m1c[2], s1c[2], b1c[2], m2c[2], s2c[2], b2c[2];
#pragma unroll
  for (int k = 0; k < 2; ++k) {
    int o = ob + og + k;
    bs[k] = hasb ? bias[o] : 0.f;
    if (has1) { float g = bn1[o]; b1c[k] = bn1[O + o]; m1c[k] = bn1[2 * O + o];
                s1c[k] = g / sqrtf(bn1[3 * O + o] + BN_EPS); }
    if (has2) { float g = bn2[o]; b2c[k] = bn2[O + o]; m2c[k] = bn2[2 * O + o];
                s2c[k] = g / sqrtf(bn2[3 * O + o] + BN_EPS); }
  }

  float st[2][4] = {};   // LIF membrane per (o-row, v)
  const float* WTb = WT + ob;

  for (int t = 0; t < TT; ++t) {
    const int tb = t * BB + b;
    const u32* Mrow = InM + (size_t)tb * C * 4;

    // ---- merge producer slot lists via wave prefix scan (ascending order) ----
    __syncthreads();                       // protect slist/sAct reuse
    u32 c = 0;
    if (tid < nblkI) c = cntI[(size_t)tb * nblkI + tid];
    u32 xs = c;
#pragma unroll
    for (int off = 1; off < 64; off <<= 1) {
      u32 y = __shfl_up(xs, off);
      if (lane >= off) xs += y;
    }
    if (lane == 63 && wv < 2) sWS[wv] = xs;
    __syncthreads();
    if (tid < nblkI && c) {
      u32 o = ((wv == 1) ? sWS[0] : 0u) + xs - c;
      const u16* src = idsI + ((size_t)tb * nblkI + tid) * 16;
      for (u32 k = 0; k < c; ++k) slist[o + k] = src[k];
    }
    if (tid == 0) runbS = sWS[0] + ((nblkI > 64) ? sWS[1] : 0u);
    __syncthreads();
    const int n = (int)runbS;

    // ---- K loop: 64-channel LDS-staged tiles ----
    float acc[2][4] = {};
    for (int a0 = 0; a0 < n; a0 += 64) {
      int m = n - a0; if (m > 64) m = 64;
      if (a0) __syncthreads();             // protect sW/sM reuse
      {
        int cc = tid >> 2, q = (tid & 3) * 4;
        if (cc < m) {
          int ch = slist[a0 + cc];
          *(float4*)&sW[cc][q] = *(const float4*)&WTb[(size_t)ch * O + q];
          sM[cc][tid & 3] = Mrow[(size_t)ch * 4 + (tid & 3)];
        }
      }
      __syncthreads();
#pragma unroll 4
      for (int i = 0; i < m; ++i) {
        u32 nib = sM[i][wword] >> sh4;
        float2 w2 = *(const float2*)&sW[i][og];
        float f0 = (float)(nib & 1u);
        float f1 = (float)((nib >> 1) & 1u);
        float f2 = (float)((nib >> 2) & 1u);
        float f3 = (float)((nib >> 3) & 1u);
        acc[0][0] += w2.x * f0; acc[0][1] += w2.x * f1; acc[0][2] += w2.x * f2; acc[0][3] += w2.x * f3;
        acc[1][0] += w2.y * f0; acc[1][1] += w2.y * f1; acc[1][2] += w2.y * f2; acc[1][3] += w2.y * f3;
      }
    }

    // ---- epilogue: bias -> bn1 -> bn2 -> resid -> LIF -> masks + activity ----
#pragma unroll
    for (int k = 0; k < 2; ++k) {
      float a[4] = {acc[k][0], acc[k][1], acc[k][2], acc[k][3]};
      if (hasb) {
#pragma unroll
        for (int j = 0; j < 4; ++j) a[j] += bs[k];
      }
      if (has1) {
#pragma unroll
        for (int j = 0; j < 4; ++j) a[j] = (a[j] - m1c[k]) * s1c[k] + b1c[k];
      }
      if (has2) {
#pragma unroll
        for (int j = 0; j < 4; ++j) a[j] = (a[j] - m2c[k]) * s2c[k] + b2c[k];
      }
      size_t orow = (size_t)tb * O + ob + og + k;
      if (OutPre) {
        size_t oi = orow * VV + vg * 4;
        float4 r = *(const float4*)&resid[oi];
        a[0] += r.x; a[1] += r.y; a[2] += r.z; a[3] += r.w;
        float4 wr = {a[0], a[1], a[2], a[3]};
        *(float4*)&OutPre[oi] = wr;
      }
      u32 nib = 0;
#pragma unroll
      for (int j = 0; j < 4; ++j) {
        st[k][j] += (a[j] - st[k][j]) * 0.5f;
        float sp = (st[k][j] >= vth) ? 1.f : 0.f;
        st[k][j] *= (1.f - sp);
        nib |= (sp != 0.f) ? (1u << j) : 0u;
      }
      u32 wmask = nib << sh4;
      wmask |= __shfl_xor(wmask, 1);
      wmask |= __shfl_xor(wmask, 2);
      wmask |= __shfl_xor(wmask, 4);
      if ((vg & 7) == 0) SpkM[orow * 4 + wword] = wmask;
      u32 aw = wmask | __shfl_xor(wmask, 8);
      aw |= __shfl_xor(aw, 16);
      if (vg == 0) sAct[og + k] = aw ? 1 : 0;
    }
    if (cntO) {
      __syncthreads();
      if (tid == 0) {
        int cc = 0;
        for (int i = 0; i < 16; ++i)
          if (sAct[i])
            idsO[((size_t)tb * gridDim.y + blockIdx.y) * 16 + cc++] = (u16)(ob + i);
        cntO[(size_t)tb * gridDim.y + blockIdx.y] = cc;
      }
    }
  }
}

// ---------------- fused attention: KV=popcount(K&V); O=Q.KV*0.125; LIF(0.5) ----------------
__global__ __launch_bounds__(256) void attn_fused(const u32* __restrict__ Qm,
    const u32* __restrict__ Km, const u32* __restrict__ Vm, u32* __restrict__ Om,
    u32* __restrict__ cntO, u16* __restrict__ idsO)
{
  const int b = blockIdx.x, hh = blockIdx.y, dh = blockIdx.z;
  const int tid = threadIdx.x, lane = tid & 63;
  __shared__ float sQ[64][132];
  __shared__ float sKV[64][36];
  __shared__ u64 sKm[64][2], sQm[64][2], sVm[32][2];
  __shared__ u32 sQnz[64];
  __shared__ u8 sAct[32];
  const int np = lane * 2;
  const int dg = (tid >> 6) * 8;
  float st[8][2] = {};
  for (int t = 0; t < TT; ++t) {
    const int tb = t * BB + b;
    __syncthreads();
    if (tid < 64) {
      uint4 q = *(const uint4*)&Qm[((size_t)tb * EE + hh * 64 + tid) * 4];
      sQm[tid][0] = ((u64)q.y << 32) | q.x; sQm[tid][1] = ((u64)q.w << 32) | q.z;
      sQnz[tid] = q.x | q.y | q.z | q.w;
      uint4 k = *(const uint4*)&Km[((size_t)tb * EE + hh * 64 + tid) * 4];
      sKm[tid][0] = ((u64)k.y << 32) | k.x; sKm[tid][1] = ((u64)k.w << 32) | k.z;
    } else if (tid < 96) {
      int d = tid - 64;
      uint4 v = *(const uint4*)&Vm[((size_t)tb * EE + hh * 64 + dh * 32 + d) * 4];
      sVm[d][0] = ((u64)v.y << 32) | v.x; sVm[d][1] = ((u64)v.w << 32) | v.z;
    }
    __syncthreads();
    {
      int c = tid >> 2, dq = (tid & 3) * 8;
      u64 k0 = sKm[c][0], k1 = sKm[c][1];
#pragma unroll
      for (int i = 0; i < 8; ++i) {
        int d = dq + i;
        int p = __popcll(k0 & sVm[d][0]) + __popcll(k1 & sVm[d][1]);
        sKV[c][d] = (float)p;
      }
    }
    {
      int c = tid >> 2, nq = (tid & 3) * 32;
      u64 qw = sQm[c][nq >> 6] >> (nq & 32);
#pragma unroll
      for (int kk = 0; kk < 8; ++kk) {
        float4 f = {(qw >> (kk * 4)) & 1 ? 1.f : 0.f,
                    (qw >> (kk * 4 + 1)) & 1 ? 1.f : 0.f,
                    (qw >> (kk * 4 + 2)) & 1 ? 1.f : 0.f,
                    (qw >> (kk * 4 + 3)) & 1 ? 1.f : 0.f};
        *(float4*)&sQ[c][nq + kk * 4] = f;
      }
    }
    __syncthreads();
    float acc[8][2] = {};
    for (int c = 0; c < 64; ++c) {
      if (!sQnz[c]) continue;
      float2 q2 = *(const float2*)&sQ[c][np];
      float4 wa = *(const float4*)&sKV[c][dg];
      float4 wb = *(const float4*)&sKV[c][dg + 4];
      float w8[8] = {wa.x, wa.y, wa.z, wa.w, wb.x, wb.y, wb.z, wb.w};
#pragma unroll
      for (int i = 0; i < 8; ++i) { acc[i][0] += w8[i] * q2.x; acc[i][1] += w8[i] * q2.y; }
    }
#pragma unroll
    for (int i = 0; i < 8; ++i) {
      float a0 = acc[i][0] * 0.125f, a1 = acc[i][1] * 0.125f;
      st[i][0] += (a0 - st[i][0]) * 0.5f; st[i][1] += (a1 - st[i][1]) * 0.5f;
      float s0 = (st[i][0] >= 0.5f) ? 1.f : 0.f, s1 = (st[i][1] >= 0.5f) ? 1.f : 0.f;
      st[i][0] *= (1.f - s0); st[i][1] *= (1.f - s1);
      u32 two = ((s0 != 0.f) ? 1u : 0u) | ((s1 != 0.f) ? 2u : 0u);
      u32 wmask = two << ((lane & 15) * 2);
      wmask |= __shfl_xor(wmask, 1);
      wmask |= __shfl_xor(wmask, 2);
      wmask |= __shfl_xor(wmask, 4);
      wmask |= __shfl_xor(wmask, 8);
      if ((lane & 15) == 0)
        Om[((size_t)tb * EE + hh * 64 + dh * 32 + dg + i) * 4 + (lane >> 4)] = wmask;
      u32 aw = wmask | __shfl_xor(wmask, 16);
      aw |= __shfl_xor(aw, 32);
      if (lane == 0) sAct[dg + i] = aw ? 1 : 0;
    }
    __syncthreads();
    if (tid < 2) {
      int slot = hh * 4 + dh * 2 + tid;
      int c = 0;
      for (int i = 0; i < 16; ++i)
        if (sAct[tid * 16 + i])
          idsO[((size_t)tb * 32 + slot) * 16 + c++] = (u16)(hh * 64 + dh * 32 + tid * 16 + i);
      cntO[(size_t)tb * 32 + slot] = c;
    }
  }
}

// ---------------- head: mean over V then LIF over t ----------------
__global__ __launch_bounds__(256) void mean_lif(const float* __restrict__ h,
    float* __restrict__ sh)
{
  int i = blockIdx.x * 256 + threadIdx.x;
  float v = 0.f;
#pragma unroll
  for (int t = 0; t < TT; ++t) {
    const float* p = h + ((size_t)t * BB * EE + i) * VV;
    float s = 0.f;
#pragma unroll
    for (int q = 0; q < VV; q += 4) {
      float4 x = *(const float4*)&p[q];
      s += x.x + x.y + x.z + x.w;
    }
    float hm = s * (1.f / 128.f);
    v += (hm - v) * 0.5f;
    float sp = (v >= 1.f) ? 1.f : 0.f;
    sh[(size_t)t * (BB * EE) + i] = sp;
    v *= (1.f - sp);
  }
}

__global__ __launch_bounds__(256) void head_k2(const float* __restrict__ sh,
    const float* __restrict__ hw, const float* __restrict__ hb,
    float* __restrict__ out)
{
  int g = blockIdx.x * 4 + (threadIdx.x >> 6);
  int lane = threadIdx.x & 63;
  if (g >= BB * 11) return;
  int b = g / 11, n = g % 11;
  float s = 0.f;
#pragma unroll
  for (int t = 0; t < TT; ++t) {
    const float* sp = sh + (size_t)t * (BB * EE) + b * EE;
    const float* wp = hw + n * EE;
    float ss = 0.f;
#pragma unroll
    for (int e = 0; e < EE; e += 64) ss += sp[e + lane] * wp[e + lane];
#pragma unroll
    for (int off = 32; off; off >>= 1) ss += __shfl_down(ss, off);
    if (lane == 0) s += ss;
  }
  if (lane == 0) out[g] = s * 0.25f + hb[n];
}

// ---------------- launch ----------------
extern "C" void kernel_launch(void* const* d_in, const int* in_sizes, int n_in,
                              void* d_out, int out_size, void* d_ws, size_t ws_size,
                              hipStream_t stream) {
  const float* x       = (const float*)d_in[0];
  const float* pe_w    = (const float*)d_in[1];
  const float* pe_bn   = (const float*)d_in[2];
  const float* qkvp_w  = (const float*)d_in[3];
  const float* qkvp_bn = (const float*)d_in[4];
  const float* fc1_w   = (const float*)d_in[5];
  const float* fc1_b   = (const float*)d_in[6];
  const float* fc1_bn  = (const float*)d_in[7];
  const float* fc2_w   = (const float*)d_in[8];
  const float* fc2_b   = (const float*)d_in[9];
  const float* fc2_bn  = (const float*)d_in[10];
  const float* head_w  = (const float*)d_in[11];
  const float* head_b  = (const float*)d_in[12];
  float* out = (float*)d_out;

  const size_t NH = (size_t)TT * BB * EE * VV;       // 4194304
  float* ws = (float*)d_ws;
  float* h   = ws;
  float* wq  = h + NH;
  float* w1  = wq + (size_t)6 * 4 * EE * EE;
  float* w2  = w1 + (size_t)6 * HIDC * EE;
  float* sh  = w2 + (size_t)6 * EE * HIDC;
  u32* mIn  = (u32*)(sh + (size_t)TT * BB * EE);
  u32* mQKV = mIn + (size_t)64 * EE * 4;
  u32* mO   = mQKV + (size_t)3 * 64 * EE * 4;
  u32* mMlp = mO + (size_t)64 * EE * 4;
  u32* mHid = mMlp + (size_t)64 * EE * 4;            // 64*HIDC*4
  u32* cntIn = mHid + (size_t)64 * HIDC * 4;         // [64][32]
  u32* cntO  = cntIn + 64 * 32;
  u32* cntM  = cntO + 64 * 32;
  u32* cntH  = cntM + 64 * 32;                       // [64][128]
  u16* idsIn = (u16*)(cntH + 64 * 128);              // [64][32][16]
  u16* idsO  = idsIn + (size_t)64 * 32 * 16;
  u16* idsM  = idsO + (size_t)64 * 32 * 16;
  u16* idsH  = idsM + (size_t)64 * 32 * 16;          // [64][128][16]

  u32* mQ = mQKV;
  u32* mK = mQKV + (size_t)64 * EE * 4;
  u32* mV = mQKV + (size_t)2 * 64 * EE * 4;

  trans_all<<<dim3(1024, 6, 6), 256, 0, stream>>>(qkvp_w, fc1_w, fc2_w, wq, w1, w2);
  pe_lif<<<dim3(BB, EE / 16), 256, 0, stream>>>(x, pe_w, pe_bn, h, mIn, cntIn, idsIn);

  for (int d = 0; d < 6; ++d) {
    const float* bn1p = qkvp_bn + (size_t)d * 4 * 2 * 4 * EE;
    // qkv (z=3): masks -> Q/K/V masks
    gemm_fused<<<dim3(BB, EE / 16, 3), 256, 0, stream>>>(mIn, cntIn, idsIn, 32,
        wq + (size_t)d * 4 * EE * EE, nullptr, nullptr, mQ, nullptr, nullptr,
        nullptr, bn1p, bn1p + 4 * EE, EE, EE, 1.f,
        (long)EE * EE, (long)64 * EE * 4, (long)2 * 4 * EE);
    attn_fused<<<dim3(BB, 8, 2), 256, 0, stream>>>(mQ, mK, mV, mO, cntO, idsO);
    // proj: + resid -> h; LIF(1) -> mMlp + lists
    gemm_fused<<<dim3(BB, EE / 16, 1), 256, 0, stream>>>(mO, cntO, idsO, 32,
        wq + ((size_t)d * 4 + 3) * EE * EE, h, h, mMlp, cntM, idsM,
        nullptr, bn1p + 3 * (2 * 4 * EE), bn1p + 3 * (2 * 4 * EE) + 4 * EE,
        EE, EE, 1.f, 0, 0, 0);
    // fc1: bias+bn; LIF(1) -> mHid + lists
    gemm_fused<<<dim3(BB, HIDC / 16, 1), 256, 0, stream>>>(mMlp, cntM, idsM, 32,
        w1 + (size_t)d * HIDC * EE, nullptr, nullptr, mHid, cntH, idsH,
        fc1_b + (size_t)d * HIDC, fc1_bn + (size_t)d * 4 * HIDC, nullptr,
        EE, HIDC, 1.f, 0, 0, 0);
    // fc2: bias+bn + resid -> h; LIF(1) -> mIn + lists (next layer input)
    gemm_fused<<<dim3(BB, EE / 16, 1), 256, 0, stream>>>(mHid, cntH, idsH, 128,
        w2 + (size_t)d * EE * HIDC, h, h, mIn, cntIn, idsIn,
        fc2_b + (size_t)d * EE, fc2_bn + (size_t)d * 4 * EE, nullptr,
        HIDC, EE, 1.f, 0, 0, 0);
  }

  mean_lif<<<32, 256, 0, stream>>>(h, sh);
  head_k2<<<44, 256, 0, stream>>>(sh, head_w, head_b, out);
}

// Round 10
// 516.762 us; speedup vs baseline: 1.7370x; 1.4867x over previous
//
#include <hip/hip_runtime.h>

#define TT 4
#define BB 16
#define VV 128
#define EE 512
#define HIDC 2048
#define BN_EPS 1e-5f

typedef unsigned int u32;
typedef unsigned long long u64;
typedef unsigned short u16;
typedef unsigned char u8;

// Mask layout: [b][c][t][4] u32  (row = (b*C+c)*16 words; 64B per (b,c))

// ---------------- all-layer weight transpose: WT[c][o] ----------------
__global__ __launch_bounds__(256) void trans_all(const float* __restrict__ qw,
    const float* __restrict__ f1w, const float* __restrict__ f2w,
    float* __restrict__ wq, float* __restrict__ w1, float* __restrict__ w2)
{
  const int d = blockIdx.z, zz = blockIdx.y;
  const float* src; float* dst; int O, C;
  if (zz < 4)      { src = qw + ((size_t)d * 4 + zz) * EE * EE; dst = wq + ((size_t)d * 4 + zz) * EE * EE; O = EE; C = EE; }
  else if (zz == 4){ src = f1w + (size_t)d * HIDC * EE; dst = w1 + (size_t)d * HIDC * EE; O = HIDC; C = EE; }
  else             { src = f2w + (size_t)d * EE * HIDC; dst = w2 + (size_t)d * EE * HIDC; O = EE; C = HIDC; }
  const int tc_n = C >> 5, to_n = O >> 5;
  const int bx = blockIdx.x;
  if (bx >= tc_n * to_n) return;
  const int tc = bx % tc_n, to = bx / tc_n;
  __shared__ float t[32][33];
  const int tx = threadIdx.x & 31, ty = threadIdx.x >> 5;
#pragma unroll
  for (int k = 0; k < 4; ++k) {
    int o = to * 32 + ty + k * 8, c = tc * 32 + tx;
    t[ty + k * 8][tx] = src[(size_t)o * C + c];
  }
  __syncthreads();
#pragma unroll
  for (int k = 0; k < 4; ++k) {
    int c = tc * 32 + ty + k * 8, o = to * 32 + tx;
    dst[(size_t)c * O + o] = t[tx][ty + k * 8];
  }
}

// ---------------- patch embed + BN + LIF -> h + masks (new layout) + union lists ----------------
__global__ __launch_bounds__(256) void pe_lif(const float* __restrict__ x,
    const float* __restrict__ w, const float* __restrict__ bnp,
    float* __restrict__ h, u32* __restrict__ mIn,
    u32* __restrict__ cnt, u16* __restrict__ ids)
{
  const int b = blockIdx.x, eb = blockIdx.y;
  const int tid = threadIdx.x;
  const int chl = tid >> 4, e = eb * 16 + chl;
  const int vs = (tid & 15) * 8;
  __shared__ u8 sB[16][16];
  __shared__ u8 sActAny[16];
  if (tid < 16) sActAny[tid] = 0;
  const float w0 = w[e * 2], w1 = w[e * 2 + 1];
  const float gg = bnp[e], be = bnp[EE + e], mm = bnp[2 * EE + e], vr = bnp[3 * EE + e];
  const float sc = gg / sqrtf(vr + BN_EPS);
  float vm[8];
#pragma unroll
  for (int k = 0; k < 8; ++k) vm[k] = 0.f;
  __syncthreads();
  for (int t = 0; t < TT; ++t) {
    const int tb = t * BB + b;
    const float* xb = x + (size_t)tb * 2 * VV + vs;
    float4 x0a = *(const float4*)&xb[0],   x0b = *(const float4*)&xb[4];
    float4 x1a = *(const float4*)&xb[VV],  x1b = *(const float4*)&xb[VV + 4];
    float a[8] = {x0a.x, x0a.y, x0a.z, x0a.w, x0b.x, x0b.y, x0b.z, x0b.w};
    float c1[8] = {x1a.x, x1a.y, x1a.z, x1a.w, x1b.x, x1b.y, x1b.z, x1b.w};
    u32 byte = 0;
#pragma unroll
    for (int k = 0; k < 8; ++k) {
      a[k] = (w0 * a[k] + w1 * c1[k] - mm) * sc + be;
      vm[k] += (a[k] - vm[k]) * 0.5f;
      float sp = (vm[k] >= 1.f) ? 1.f : 0.f;
      vm[k] *= (1.f - sp);
      byte |= (sp != 0.f) ? (1u << k) : 0u;
    }
    size_t ho = ((size_t)tb * EE + e) * VV + vs;
    float4 ha = {a[0], a[1], a[2], a[3]}, hb = {a[4], a[5], a[6], a[7]};
    *(float4*)&h[ho] = ha; *(float4*)&h[ho + 4] = hb;
    sB[chl][tid & 15] = (u8)byte;
    __syncthreads();
    if (tid < 16) {
      uint4 mw = *(const uint4*)&sB[tid][0];
      *(uint4*)&mIn[((size_t)b * EE + eb * 16 + tid) * 16 + t * 4] = mw;
      if (mw.x | mw.y | mw.z | mw.w) sActAny[tid] = 1;
    }
    __syncthreads();
  }
  if (tid == 0) {
    int c = 0;
    for (int i = 0; i < 16; ++i)
      if (sActAny[i]) ids[((size_t)b * 32 + eb) * 16 + c++] = (u16)(eb * 16 + i);
    cnt[(size_t)b * 32 + eb] = c;
  }
}

// ---------------- t-fused sparse bit-spike GEMM ----------------
// grid (B, O/16, nz), 256 thr. Thread: 2o x 4v x 4t accumulators.
__global__ __launch_bounds__(256) void gemm_fused(
    const u32* __restrict__ InM, const u32* __restrict__ cntI,
    const u16* __restrict__ idsI, int nblkI,
    const float* __restrict__ WT, float* __restrict__ OutPre,
    const float* __restrict__ resid, u32* __restrict__ SpkM,
    u32* __restrict__ cntO, u16* __restrict__ idsO,
    const float* __restrict__ bias, const float* __restrict__ bn1,
    const float* __restrict__ bn2,
    int C, int O, float vth, long wtZ, long spkZ, long bnZ)
{
  const int b = blockIdx.x, ob = blockIdx.y * 16, z = blockIdx.z;
  const int tid = threadIdx.x, lane = tid & 63, wv = tid >> 6;
  WT += (long)z * wtZ; SpkM += (long)z * spkZ;
  if (bn1) bn1 += (long)z * bnZ;
  if (bn2) bn2 += (long)z * bnZ;

  __shared__ u16 slist[2048];
  __shared__ alignas(16) float sW[64][16];
  __shared__ alignas(16) u32 sM[64][16];
  __shared__ u32 sWS[2];
  __shared__ u32 runbS;
  __shared__ u8 sAct[16];

  const int og = (tid >> 5) * 2;     // 8 groups x 2 o
  const int vg = tid & 31;           // 4 v each
  const int wword = vg >> 3;
  const int sh4 = (vg & 7) * 4;
  const bool hasb = (bias != nullptr), has1 = (bn1 != nullptr), has2 = (bn2 != nullptr);

  float bs[2], m1c[2], s1c[2], b1c[2], m2c[2], s2c[2], b2c[2];
#pragma unroll
  for (int k = 0; k < 2; ++k) {
    int o = ob + og + k;
    bs[k] = hasb ? bias[o] : 0.f;
    if (has1) { float g = bn1[o]; b1c[k] = bn1[O + o]; m1c[k] = bn1[2 * O + o];
                s1c[k] = g / sqrtf(bn1[3 * O + o] + BN_EPS); }
    if (has2) { float g = bn2[o]; b2c[k] = bn2[O + o]; m2c[k] = bn2[2 * O + o];
                s2c[k] = g / sqrtf(bn2[3 * O + o] + BN_EPS); }
  }

  // ---- merge union slot lists once (ascending -> exact fp order) ----
  u32 c = 0;
  if (tid < nblkI) c = cntI[(size_t)b * nblkI + tid];
  u32 xs = c;
#pragma unroll
  for (int off = 1; off < 64; off <<= 1) {
    u32 y = __shfl_up(xs, off);
    if (lane >= off) xs += y;
  }
  if (lane == 63 && wv < 2) sWS[wv] = xs;
  __syncthreads();
  if (tid < nblkI && c) {
    u32 o = ((wv == 1) ? sWS[0] : 0u) + xs - c;
    const u16* src = idsI + ((size_t)b * nblkI + tid) * 16;
    for (u32 k = 0; k < c; ++k) slist[o + k] = src[k];
  }
  if (tid == 0) runbS = sWS[0] + ((nblkI > 64) ? sWS[1] : 0u);
  __syncthreads();
  const int n = (int)runbS;

  const u32* Mb = InM + (size_t)b * C * 16;
  const float* WTb = WT + ob;

  // ---- K loop: 64-ch LDS stages carrying all 4 t masks; 32 indep acc chains ----
  float acc[TT][2][4] = {};
  for (int a0 = 0; a0 < n; a0 += 64) {
    int m = n - a0; if (m > 64) m = 64;
    if (a0) __syncthreads();
    {
      int cc = tid >> 2, part = tid & 3;
      if (cc < m) {
        int ch = slist[a0 + cc];
        *(float4*)&sW[cc][part * 4] = *(const float4*)&WTb[(size_t)ch * O + part * 4];
        *(uint4*)&sM[cc][part * 4]  = *(const uint4*)&Mb[(size_t)ch * 16 + part * 4];
      }
    }
    __syncthreads();
#pragma unroll 2
    for (int i = 0; i < m; ++i) {
      float2 w2 = *(const float2*)&sW[i][og];
#pragma unroll
      for (int t = 0; t < TT; ++t) {
        u32 wd = sM[i][t * 4 + wword];
        if (wd) {
          u32 nib = wd >> sh4;
          float f0 = (float)(nib & 1u);
          float f1 = (float)((nib >> 1) & 1u);
          float f2 = (float)((nib >> 2) & 1u);
          float f3 = (float)((nib >> 3) & 1u);
          acc[t][0][0] += w2.x * f0; acc[t][0][1] += w2.x * f1;
          acc[t][0][2] += w2.x * f2; acc[t][0][3] += w2.x * f3;
          acc[t][1][0] += w2.y * f0; acc[t][1][1] += w2.y * f1;
          acc[t][1][2] += w2.y * f2; acc[t][1][3] += w2.y * f3;
        }
      }
    }
  }

  // ---- epilogue: per t: bias -> bn1 -> bn2 -> resid -> LIF -> masks; union act ----
  float st[2][4] = {};
  u32 actU[2] = {0, 0};
#pragma unroll
  for (int t = 0; t < TT; ++t) {
    const int tb = t * BB + b;
#pragma unroll
    for (int k = 0; k < 2; ++k) {
      float a[4] = {acc[t][k][0], acc[t][k][1], acc[t][k][2], acc[t][k][3]};
      if (hasb) {
#pragma unroll
        for (int j = 0; j < 4; ++j) a[j] += bs[k];
      }
      if (has1) {
#pragma unroll
        for (int j = 0; j < 4; ++j) a[j] = (a[j] - m1c[k]) * s1c[k] + b1c[k];
      }
      if (has2) {
#pragma unroll
        for (int j = 0; j < 4; ++j) a[j] = (a[j] - m2c[k]) * s2c[k] + b2c[k];
      }
      if (OutPre) {
        size_t oi = ((size_t)tb * O + ob + og + k) * VV + vg * 4;
        float4 r = *(const float4*)&resid[oi];
        a[0] += r.x; a[1] += r.y; a[2] += r.z; a[3] += r.w;
        float4 wr = {a[0], a[1], a[2], a[3]};
        *(float4*)&OutPre[oi] = wr;
      }
      u32 nib = 0;
#pragma unroll
      for (int j = 0; j < 4; ++j) {
        st[k][j] += (a[j] - st[k][j]) * 0.5f;
        float sp = (st[k][j] >= vth) ? 1.f : 0.f;
        st[k][j] *= (1.f - sp);
        nib |= (sp != 0.f) ? (1u << j) : 0u;
      }
      u32 wmask = nib << sh4;
      wmask |= __shfl_xor(wmask, 1);
      wmask |= __shfl_xor(wmask, 2);
      wmask |= __shfl_xor(wmask, 4);
      if ((vg & 7) == 0)
        SpkM[((size_t)b * O + ob + og + k) * 16 + t * 4 + wword] = wmask;
      u32 aw = wmask | __shfl_xor(wmask, 8);
      aw |= __shfl_xor(aw, 16);
      actU[k] |= aw;
    }
  }
  if (vg == 0) { sAct[og] = actU[0] ? 1 : 0; sAct[og + 1] = actU[1] ? 1 : 0; }
  if (cntO) {
    __syncthreads();
    if (tid == 0) {
      int cc = 0;
      for (int i = 0; i < 16; ++i)
        if (sAct[i])
          idsO[((size_t)b * gridDim.y + blockIdx.y) * 16 + cc++] = (u16)(ob + i);
      cntO[(size_t)b * gridDim.y + blockIdx.y] = cc;
    }
  }
}

// ---------------- t-fused attention: KV=popcount(K&V); O=Q.KV*0.125; LIF(0.5) ----------------
// grid (B, 8 heads, 4 d-quarters), 256 thr. Thread: 4d x 2n x 4t accumulators.
__global__ __launch_bounds__(256) void attn_fused(const u32* __restrict__ Qm,
    const u32* __restrict__ Km, const u32* __restrict__ Vm, u32* __restrict__ Om,
    u32* __restrict__ cntO, u16* __restrict__ idsO)
{
  const int b = blockIdx.x, hh = blockIdx.y, dq = blockIdx.z;
  const int tid = threadIdx.x, lane = tid & 63, wave = tid >> 6;
  __shared__ u64 sKm[TT][64][2];
  __shared__ u64 sVm[TT][16][2];
  __shared__ alignas(16) u32 sQw[TT][64][4];
  __shared__ u8 sQnz[TT][64];
  __shared__ alignas(16) float sKV[64][20];
  __shared__ u8 sAct[16];

  // ---- stage all 4 t's masks ----
  {
    int c = tid >> 2, t = tid & 3;
    size_t rb = ((size_t)b * EE + hh * 64 + c) * 16 + t * 4;
    uint4 q = *(const uint4*)&Qm[rb];
    *(uint4*)&sQw[t][c][0] = q;
    sQnz[t][c] = (q.x | q.y | q.z | q.w) ? 1 : 0;
    uint4 k = *(const uint4*)&Km[rb];
    sKm[t][c][0] = ((u64)k.y << 32) | k.x;
    sKm[t][c][1] = ((u64)k.w << 32) | k.z;
    if (c < 16) {
      uint4 v = *(const uint4*)&Vm[((size_t)b * EE + hh * 64 + dq * 16 + c) * 16 + t * 4];
      sVm[t][c][0] = ((u64)v.y << 32) | v.x;
      sVm[t][c][1] = ((u64)v.w << 32) | v.z;
    }
  }
  __syncthreads();

  const int np = lane * 2;
  const int qword = lane >> 4, qsh = np & 31;
  float acc[TT][4][2] = {};
  for (int t = 0; t < TT; ++t) {
    // KV = popcount(K & V): [c][16 local d]
    {
      int c = tid >> 2, d0 = (tid & 3) * 4;
      u64 k0 = sKm[t][c][0], k1 = sKm[t][c][1];
#pragma unroll
      for (int i = 0; i < 4; ++i) {
        int d = d0 + i;
        sKV[c][d] = (float)(__popcll(k0 & sVm[t][d][0]) + __popcll(k1 & sVm[t][d][1]));
      }
    }
    __syncthreads();
    for (int c = 0; c < 64; ++c) {
      if (!sQnz[t][c]) continue;
      u32 two = (sQw[t][c][qword] >> qsh) & 3u;
      if (two) {
        float f0 = (float)(two & 1u);
        float f1 = (float)(two >> 1);
        float4 kv = *(const float4*)&sKV[c][wave * 4];
        acc[t][0][0] += kv.x * f0; acc[t][0][1] += kv.x * f1;
        acc[t][1][0] += kv.y * f0; acc[t][1][1] += kv.y * f1;
        acc[t][2][0] += kv.z * f0; acc[t][2][1] += kv.z * f1;
        acc[t][3][0] += kv.w * f0; acc[t][3][1] += kv.w * f1;
      }
    }
    __syncthreads();
  }

  // ---- epilogue: LIF(0.5) across t in regs; masks + union activity ----
  float st[4][2] = {};
  u32 actU[4] = {0, 0, 0, 0};
#pragma unroll
  for (int t = 0; t < TT; ++t) {
#pragma unroll
    for (int i = 0; i < 4; ++i) {
      float a0 = acc[t][i][0] * 0.125f, a1 = acc[t][i][1] * 0.125f;
      st[i][0] += (a0 - st[i][0]) * 0.5f;
      st[i][1] += (a1 - st[i][1]) * 0.5f;
      float s0 = (st[i][0] >= 0.5f) ? 1.f : 0.f;
      float s1 = (st[i][1] >= 0.5f) ? 1.f : 0.f;
      st[i][0] *= (1.f - s0); st[i][1] *= (1.f - s1);
      u32 two = ((s0 != 0.f) ? 1u : 0u) | ((s1 != 0.f) ? 2u : 0u);
      u32 wmask = two << qsh;
      wmask |= __shfl_xor(wmask, 1);
      wmask |= __shfl_xor(wmask, 2);
      wmask |= __shfl_xor(wmask, 4);
      wmask |= __shfl_xor(wmask, 8);
      if ((lane & 15) == 0)
        Om[((size_t)b * EE + hh * 64 + dq * 16 + wave * 4 + i) * 16 + t * 4 + qword] = wmask;
      u32 aw = wmask | __shfl_xor(wmask, 16);
      aw |= __shfl_xor(aw, 32);
      actU[i] |= aw;
    }
  }
  if (lane == 0) {
#pragma unroll
    for (int i = 0; i < 4; ++i) sAct[wave * 4 + i] = actU[i] ? 1 : 0;
  }
  __syncthreads();
  if (tid == 0) {
    int slot = hh * 4 + dq;
    int c = 0;
    for (int i = 0; i < 16; ++i)
      if (sAct[i]) idsO[((size_t)b * 32 + slot) * 16 + c++] = (u16)(hh * 64 + dq * 16 + i);
    cntO[(size_t)b * 32 + slot] = c;
  }
}

// ---------------- head: mean over V then LIF over t ----------------
__global__ __launch_bounds__(256) void mean_lif(const float* __restrict__ h,
    float* __restrict__ sh)
{
  int i = blockIdx.x * 256 + threadIdx.x;
  float v = 0.f;
#pragma unroll
  for (int t = 0; t < TT; ++t) {
    const float* p = h + ((size_t)t * BB * EE + i) * VV;
    float s = 0.f;
#pragma unroll
    for (int q = 0; q < VV; q += 4) {
      float4 x = *(const float4*)&p[q];
      s += x.x + x.y + x.z + x.w;
    }
    float hm = s * (1.f / 128.f);
    v += (hm - v) * 0.5f;
    float sp = (v >= 1.f) ? 1.f : 0.f;
    sh[(size_t)t * (BB * EE) + i] = sp;
    v *= (1.f - sp);
  }
}

__global__ __launch_bounds__(256) void head_k2(const float* __restrict__ sh,
    const float* __restrict__ hw, const float* __restrict__ hb,
    float* __restrict__ out)
{
  int g = blockIdx.x * 4 + (threadIdx.x >> 6);
  int lane = threadIdx.x & 63;
  if (g >= BB * 11) return;
  int b = g / 11, n = g % 11;
  float s = 0.f;
#pragma unroll
  for (int t = 0; t < TT; ++t) {
    const float* sp = sh + (size_t)t * (BB * EE) + b * EE;
    const float* wp = hw + n * EE;
    float ss = 0.f;
#pragma unroll
    for (int e = 0; e < EE; e += 64) ss += sp[e + lane] * wp[e + lane];
#pragma unroll
    for (int off = 32; off; off >>= 1) ss += __shfl_down(ss, off);
    if (lane == 0) s += ss;
  }
  if (lane == 0) out[g] = s * 0.25f + hb[n];
}

// ---------------- launch ----------------
extern "C" void kernel_launch(void* const* d_in, const int* in_sizes, int n_in,
                              void* d_out, int out_size, void* d_ws, size_t ws_size,
                              hipStream_t stream) {
  const float* x       = (const float*)d_in[0];
  const float* pe_w    = (const float*)d_in[1];
  const float* pe_bn   = (const float*)d_in[2];
  const float* qkvp_w  = (const float*)d_in[3];
  const float* qkvp_bn = (const float*)d_in[4];
  const float* fc1_w   = (const float*)d_in[5];
  const float* fc1_b   = (const float*)d_in[6];
  const float* fc1_bn  = (const float*)d_in[7];
  const float* fc2_w   = (const float*)d_in[8];
  const float* fc2_b   = (const float*)d_in[9];
  const float* fc2_bn  = (const float*)d_in[10];
  const float* head_w  = (const float*)d_in[11];
  const float* head_b  = (const float*)d_in[12];
  float* out = (float*)d_out;

  const size_t NH = (size_t)TT * BB * EE * VV;       // 4194304
  float* ws = (float*)d_ws;
  float* h   = ws;
  float* wq  = h + NH;
  float* w1  = wq + (size_t)6 * 4 * EE * EE;
  float* w2  = w1 + (size_t)6 * HIDC * EE;
  float* sh  = w2 + (size_t)6 * EE * HIDC;
  // mask buffers: [b][c][t][4] u32 = 16 u32 per (b,c)
  u32* mIn  = (u32*)(sh + (size_t)TT * BB * EE);     // 16*512*16
  u32* mQKV = mIn + (size_t)BB * EE * 16;            // 3x
  u32* mO   = mQKV + (size_t)3 * BB * EE * 16;
  u32* mMlp = mO + (size_t)BB * EE * 16;
  u32* mHid = mMlp + (size_t)BB * EE * 16;           // 16*2048*16
  u32* cntIn = mHid + (size_t)BB * HIDC * 16;        // [16][32]
  u32* cntO  = cntIn + BB * 32;
  u32* cntM  = cntO + BB * 32;
  u32* cntH  = cntM + BB * 32;                       // [16][128]
  u16* idsIn = (u16*)(cntH + BB * 128);              // [16][32][16]
  u16* idsO  = idsIn + (size_t)BB * 32 * 16;
  u16* idsM  = idsO + (size_t)BB * 32 * 16;
  u16* idsH  = idsM + (size_t)BB * 32 * 16;          // [16][128][16]

  u32* mQ = mQKV;
  u32* mK = mQKV + (size_t)BB * EE * 16;
  u32* mV = mQKV + (size_t)2 * BB * EE * 16;

  trans_all<<<dim3(1024, 6, 6), 256, 0, stream>>>(qkvp_w, fc1_w, fc2_w, wq, w1, w2);
  pe_lif<<<dim3(BB, EE / 16), 256, 0, stream>>>(x, pe_w, pe_bn, h, mIn, cntIn, idsIn);

  for (int d = 0; d < 6; ++d) {
    const float* bn1p = qkvp_bn + (size_t)d * 4 * 2 * 4 * EE;
    // qkv (z=3): union lists -> Q/K/V masks (no list emission)
    gemm_fused<<<dim3(BB, EE / 16, 3), 256, 0, stream>>>(mIn, cntIn, idsIn, 32,
        wq + (size_t)d * 4 * EE * EE, nullptr, nullptr, mQ, nullptr, nullptr,
        nullptr, bn1p, bn1p + 4 * EE, EE, EE, 1.f,
        (long)EE * EE, (long)BB * EE * 16, (long)2 * 4 * EE);
    attn_fused<<<dim3(BB, 8, 4), 256, 0, stream>>>(mQ, mK, mV, mO, cntO, idsO);
    // proj: + resid -> h; LIF(1) -> mMlp + union lists
    gemm_fused<<<dim3(BB, EE / 16, 1), 256, 0, stream>>>(mO, cntO, idsO, 32,
        wq + ((size_t)d * 4 + 3) * EE * EE, h, h, mMlp, cntM, idsM,
        nullptr, bn1p + 3 * (2 * 4 * EE), bn1p + 3 * (2 * 4 * EE) + 4 * EE,
        EE, EE, 1.f, 0, 0, 0);
    // fc1: bias+bn; LIF(1) -> mHid + union lists
    gemm_fused<<<dim3(BB, HIDC / 16, 1), 256, 0, stream>>>(mMlp, cntM, idsM, 32,
        w1 + (size_t)d * HIDC * EE, nullptr, nullptr, mHid, cntH, idsH,
        fc1_b + (size_t)d * HIDC, fc1_bn + (size_t)d * 4 * HIDC, nullptr,
        EE, HIDC, 1.f, 0, 0, 0);
    // fc2: bias+bn + resid -> h; LIF(1) -> mIn + union lists (next layer input)
    gemm_fused<<<dim3(BB, EE / 16, 1), 256, 0, stream>>>(mHid, cntH, idsH, 128,
        w2 + (size_t)d * EE * HIDC, h, h, mIn, cntIn, idsIn,
        fc2_b + (size_t)d * EE, fc2_bn + (size_t)d * 4 * EE, nullptr,
        HIDC, EE, 1.f, 0, 0, 0);
  }

  mean_lif<<<32, 256, 0, stream>>>(h, sh);
  head_k2<<<44, 256, 0, stream>>>(sh, head_w, head_b, out);
}

// Round 11
// 505.142 us; speedup vs baseline: 1.7770x; 1.0230x over previous
//
#include <hip/hip_runtime.h>

#define TT 4
#define BB 16
#define VV 128
#define EE 512
#define HIDC 2048
#define BN_EPS 1e-5f

typedef unsigned int u32;
typedef unsigned long long u64;
typedef unsigned short u16;
typedef unsigned char u8;

// Mask layout (q-major): [b][c][q][t] u32, word index = q*4 + t  (64B per (b,c))

// ---------------- all-layer weight transpose: WT[c][o] ----------------
__global__ __launch_bounds__(256) void trans_all(const float* __restrict__ qw,
    const float* __restrict__ f1w, const float* __restrict__ f2w,
    float* __restrict__ wq, float* __restrict__ w1, float* __restrict__ w2)
{
  const int d = blockIdx.z, zz = blockIdx.y;
  const float* src; float* dst; int O, C;
  if (zz < 4)      { src = qw + ((size_t)d * 4 + zz) * EE * EE; dst = wq + ((size_t)d * 4 + zz) * EE * EE; O = EE; C = EE; }
  else if (zz == 4){ src = f1w + (size_t)d * HIDC * EE; dst = w1 + (size_t)d * HIDC * EE; O = HIDC; C = EE; }
  else             { src = f2w + (size_t)d * EE * HIDC; dst = w2 + (size_t)d * EE * HIDC; O = EE; C = HIDC; }
  const int tc_n = C >> 5, to_n = O >> 5;
  const int bx = blockIdx.x;
  if (bx >= tc_n * to_n) return;
  const int tc = bx % tc_n, to = bx / tc_n;
  __shared__ float t[32][33];
  const int tx = threadIdx.x & 31, ty = threadIdx.x >> 5;
#pragma unroll
  for (int k = 0; k < 4; ++k) {
    int o = to * 32 + ty + k * 8, c = tc * 32 + tx;
    t[ty + k * 8][tx] = src[(size_t)o * C + c];
  }
  __syncthreads();
#pragma unroll
  for (int k = 0; k < 4; ++k) {
    int c = tc * 32 + ty + k * 8, o = to * 32 + tx;
    dst[(size_t)c * O + o] = t[tx][ty + k * 8];
  }
}

// ---------------- patch embed + BN + LIF -> h + masks (q-major) + union lists ----------------
__global__ __launch_bounds__(256) void pe_lif(const float* __restrict__ x,
    const float* __restrict__ w, const float* __restrict__ bnp,
    float* __restrict__ h, u32* __restrict__ mIn,
    u32* __restrict__ cnt, u16* __restrict__ ids)
{
  const int b = blockIdx.x, eb = blockIdx.y;
  const int tid = threadIdx.x;
  const int chl = tid >> 4, e = eb * 16 + chl;
  const int vs = (tid & 15) * 8;
  __shared__ u8 sB[16][16];
  __shared__ u8 sActAny[16];
  if (tid < 16) sActAny[tid] = 0;
  const float w0 = w[e * 2], w1 = w[e * 2 + 1];
  const float gg = bnp[e], be = bnp[EE + e], mm = bnp[2 * EE + e], vr = bnp[3 * EE + e];
  const float sc = gg / sqrtf(vr + BN_EPS);
  float vm[8];
#pragma unroll
  for (int k = 0; k < 8; ++k) vm[k] = 0.f;
  __syncthreads();
  for (int t = 0; t < TT; ++t) {
    const int tb = t * BB + b;
    const float* xb = x + (size_t)tb * 2 * VV + vs;
    float4 x0a = *(const float4*)&xb[0],   x0b = *(const float4*)&xb[4];
    float4 x1a = *(const float4*)&xb[VV],  x1b = *(const float4*)&xb[VV + 4];
    float a[8] = {x0a.x, x0a.y, x0a.z, x0a.w, x0b.x, x0b.y, x0b.z, x0b.w};
    float c1[8] = {x1a.x, x1a.y, x1a.z, x1a.w, x1b.x, x1b.y, x1b.z, x1b.w};
    u32 byte = 0;
#pragma unroll
    for (int k = 0; k < 8; ++k) {
      a[k] = (w0 * a[k] + w1 * c1[k] - mm) * sc + be;
      vm[k] += (a[k] - vm[k]) * 0.5f;
      float sp = (vm[k] >= 1.f) ? 1.f : 0.f;
      vm[k] *= (1.f - sp);
      byte |= (sp != 0.f) ? (1u << k) : 0u;
    }
    size_t ho = ((size_t)tb * EE + e) * VV + vs;
    float4 ha = {a[0], a[1], a[2], a[3]}, hb = {a[4], a[5], a[6], a[7]};
    *(float4*)&h[ho] = ha; *(float4*)&h[ho + 4] = hb;
    sB[chl][tid & 15] = (u8)byte;
    __syncthreads();
    if (tid < 16) {
      uint4 mw = *(const uint4*)&sB[tid][0];      // words q=0..3 for this t
      size_t base = ((size_t)b * EE + eb * 16 + tid) * 16;
      mIn[base + 0 * 4 + t] = mw.x;
      mIn[base + 1 * 4 + t] = mw.y;
      mIn[base + 2 * 4 + t] = mw.z;
      mIn[base + 3 * 4 + t] = mw.w;
      if (mw.x | mw.y | mw.z | mw.w) sActAny[tid] = 1;
    }
    __syncthreads();
  }
  if (tid == 0) {
    int c = 0;
    for (int i = 0; i < 16; ++i)
      if (sActAny[i]) ids[((size_t)b * 32 + eb) * 16 + c++] = (u16)(eb * 16 + i);
    cnt[(size_t)b * 32 + eb] = c;
  }
}

// ---------------- t-fused sparse bit-spike GEMM (q-major masks) ----------------
// grid (B, O/16, nz), 256 thr. Thread: 2o x 4v x 4t accumulators.
__global__ __launch_bounds__(256) void gemm_fused(
    const u32* __restrict__ InM, const u32* __restrict__ cntI,
    const u16* __restrict__ idsI, int nblkI,
    const float* __restrict__ WT, float* __restrict__ OutPre,
    const float* __restrict__ resid, u32* __restrict__ SpkM,
    u32* __restrict__ cntO, u16* __restrict__ idsO,
    const float* __restrict__ bias, const float* __restrict__ bn1,
    const float* __restrict__ bn2,
    int C, int O, float vth, long wtZ, long spkZ, long bnZ)
{
  const int b = blockIdx.x, ob = blockIdx.y * 16, z = blockIdx.z;
  const int tid = threadIdx.x, lane = tid & 63, wv = tid >> 6;
  WT += (long)z * wtZ; SpkM += (long)z * spkZ;
  if (bn1) bn1 += (long)z * bnZ;
  if (bn2) bn2 += (long)z * bnZ;

  __shared__ u16 slist[2048];
  __shared__ alignas(16) float sW[64][16];
  __shared__ alignas(16) u32 sM[64][16];
  __shared__ u32 sWS[2];
  __shared__ u32 runbS;
  __shared__ u8 sAct[16];

  const int og = (tid >> 5) * 2;     // 8 groups x 2 o
  const int vg = tid & 31;           // 4 v each
  const int wword = vg >> 3;
  const int sh4 = (vg & 7) * 4;
  const bool hasb = (bias != nullptr), has1 = (bn1 != nullptr), has2 = (bn2 != nullptr);

  float bs[2], m1c[2], s1c[2], b1c[2], m2c[2], s2c[2], b2c[2];
#pragma unroll
  for (int k = 0; k < 2; ++k) {
    int o = ob + og + k;
    bs[k] = hasb ? bias[o] : 0.f;
    if (has1) { float g = bn1[o]; b1c[k] = bn1[O + o]; m1c[k] = bn1[2 * O + o];
                s1c[k] = g / sqrtf(bn1[3 * O + o] + BN_EPS); }
    if (has2) { float g = bn2[o]; b2c[k] = bn2[O + o]; m2c[k] = bn2[2 * O + o];
                s2c[k] = g / sqrtf(bn2[3 * O + o] + BN_EPS); }
  }

  // ---- merge union slot lists once (ascending -> exact fp order) ----
  u32 c = 0;
  if (tid < nblkI) c = cntI[(size_t)b * nblkI + tid];
  u32 xs = c;
#pragma unroll
  for (int off = 1; off < 64; off <<= 1) {
    u32 y = __shfl_up(xs, off);
    if (lane >= off) xs += y;
  }
  if (lane == 63 && wv < 2) sWS[wv] = xs;
  __syncthreads();
  if (tid < nblkI && c) {
    u32 o = ((wv == 1) ? sWS[0] : 0u) + xs - c;
    const u16* src = idsI + ((size_t)b * nblkI + tid) * 16;
    for (u32 k = 0; k < c; ++k) slist[o + k] = src[k];
  }
  if (tid == 0) runbS = sWS[0] + ((nblkI > 64) ? sWS[1] : 0u);
  __syncthreads();
  const int n = (int)runbS;

  const u32* Mb = InM + (size_t)b * C * 16;
  const float* WTb = WT + ob;

  // ---- K loop: 64-ch LDS stages; per channel: 1 b64 W read + 1 b128 mask read ----
  float acc[TT][2][4] = {};
  for (int a0 = 0; a0 < n; a0 += 64) {
    int m = n - a0; if (m > 64) m = 64;
    if (a0) __syncthreads();
    {
      int cc = tid >> 2, part = tid & 3;
      if (cc < m) {
        int ch = slist[a0 + cc];
        *(float4*)&sW[cc][part * 4] = *(const float4*)&WTb[(size_t)ch * O + part * 4];
        *(uint4*)&sM[cc][part * 4]  = *(const uint4*)&Mb[(size_t)ch * 16 + part * 4];
      }
    }
    __syncthreads();
#pragma unroll 2
    for (int i = 0; i < m; ++i) {
      float2 w2 = *(const float2*)&sW[i][og];
      uint4 m4 = *(const uint4*)&sM[i][wword * 4];   // words q=wword, t=0..3
      u32 wds[4] = {m4.x, m4.y, m4.z, m4.w};
#pragma unroll
      for (int t = 0; t < TT; ++t) {
        u32 wd = wds[t];
        if (wd) {
          u32 nib = wd >> sh4;
          float f0 = (float)(nib & 1u);
          float f1 = (float)((nib >> 1) & 1u);
          float f2 = (float)((nib >> 2) & 1u);
          float f3 = (float)((nib >> 3) & 1u);
          acc[t][0][0] += w2.x * f0; acc[t][0][1] += w2.x * f1;
          acc[t][0][2] += w2.x * f2; acc[t][0][3] += w2.x * f3;
          acc[t][1][0] += w2.y * f0; acc[t][1][1] += w2.y * f1;
          acc[t][1][2] += w2.y * f2; acc[t][1][3] += w2.y * f3;
        }
      }
    }
  }

  // ---- epilogue: per t: bias -> bn1 -> bn2 -> resid -> LIF -> masks; union act ----
  float st[2][4] = {};
  u32 actU[2] = {0, 0};
#pragma unroll
  for (int t = 0; t < TT; ++t) {
    const int tb = t * BB + b;
#pragma unroll
    for (int k = 0; k < 2; ++k) {
      float a[4] = {acc[t][k][0], acc[t][k][1], acc[t][k][2], acc[t][k][3]};
      if (hasb) {
#pragma unroll
        for (int j = 0; j < 4; ++j) a[j] += bs[k];
      }
      if (has1) {
#pragma unroll
        for (int j = 0; j < 4; ++j) a[j] = (a[j] - m1c[k]) * s1c[k] + b1c[k];
      }
      if (has2) {
#pragma unroll
        for (int j = 0; j < 4; ++j) a[j] = (a[j] - m2c[k]) * s2c[k] + b2c[k];
      }
      if (OutPre) {
        size_t oi = ((size_t)tb * O + ob + og + k) * VV + vg * 4;
        float4 r = *(const float4*)&resid[oi];
        a[0] += r.x; a[1] += r.y; a[2] += r.z; a[3] += r.w;
        float4 wr = {a[0], a[1], a[2], a[3]};
        *(float4*)&OutPre[oi] = wr;
      }
      u32 nib = 0;
#pragma unroll
      for (int j = 0; j < 4; ++j) {
        st[k][j] += (a[j] - st[k][j]) * 0.5f;
        float sp = (st[k][j] >= vth) ? 1.f : 0.f;
        st[k][j] *= (1.f - sp);
        nib |= (sp != 0.f) ? (1u << j) : 0u;
      }
      u32 wmask = nib << sh4;
      wmask |= __shfl_xor(wmask, 1);
      wmask |= __shfl_xor(wmask, 2);
      wmask |= __shfl_xor(wmask, 4);
      if ((vg & 7) == 0)
        SpkM[((size_t)b * O + ob + og + k) * 16 + wword * 4 + t] = wmask;
      u32 aw = wmask | __shfl_xor(wmask, 8);
      aw |= __shfl_xor(aw, 16);
      actU[k] |= aw;
    }
  }
  if (vg == 0) { sAct[og] = actU[0] ? 1 : 0; sAct[og + 1] = actU[1] ? 1 : 0; }
  if (cntO) {
    __syncthreads();
    if (tid == 0) {
      int cc = 0;
      for (int i = 0; i < 16; ++i)
        if (sAct[i])
          idsO[((size_t)b * gridDim.y + blockIdx.y) * 16 + cc++] = (u16)(ob + i);
      cntO[(size_t)b * gridDim.y + blockIdx.y] = cc;
    }
  }
}

// ---------------- t-fused attention: all-t KV precompute; 2 syncs total ----------------
// grid (B, 8 heads, 4 d-quarters), 256 thr. Thread: 4d x 2n x 4t accumulators.
__global__ __launch_bounds__(256) void attn_fused(const u32* __restrict__ Qm,
    const u32* __restrict__ Km, const u32* __restrict__ Vm, u32* __restrict__ Om,
    u32* __restrict__ cntO, u16* __restrict__ idsO)
{
  const int b = blockIdx.x, hh = blockIdx.y, dq = blockIdx.z;
  const int tid = threadIdx.x, lane = tid & 63, wave = tid >> 6;
  __shared__ u64 sKm[TT][64][2];
  __shared__ u64 sVm[TT][16][2];
  __shared__ u32 sQw[TT][64][4];
  __shared__ u8 sQnz[TT][64];
  __shared__ alignas(16) float sKV[TT][64][20];
  __shared__ u8 sAct[16];

  // ---- stage all 4 t's masks (q-major: word = q*4 + t) ----
  {
    int c = tid >> 2, t = tid & 3;
    size_t rb = ((size_t)b * EE + hh * 64 + c) * 16 + t;
    u32 q0 = Qm[rb], q1 = Qm[rb + 4], q2 = Qm[rb + 8], q3 = Qm[rb + 12];
    sQw[t][c][0] = q0; sQw[t][c][1] = q1; sQw[t][c][2] = q2; sQw[t][c][3] = q3;
    sQnz[t][c] = (q0 | q1 | q2 | q3) ? 1 : 0;
    u32 k0 = Km[rb], k1 = Km[rb + 4], k2 = Km[rb + 8], k3 = Km[rb + 12];
    sKm[t][c][0] = ((u64)k1 << 32) | k0;
    sKm[t][c][1] = ((u64)k3 << 32) | k2;
    if (c < 16) {
      size_t rv = ((size_t)b * EE + hh * 64 + dq * 16 + c) * 16 + t;
      u32 v0 = Vm[rv], v1 = Vm[rv + 4], v2 = Vm[rv + 8], v3 = Vm[rv + 12];
      sVm[t][c][0] = ((u64)v1 << 32) | v0;
      sVm[t][c][1] = ((u64)v3 << 32) | v2;
    }
  }
  __syncthreads();
  // ---- KV = popcount(K & V) for ALL t ----
  {
    int c = tid >> 2, t = tid & 3;
    u64 k0 = sKm[t][c][0], k1 = sKm[t][c][1];
#pragma unroll
    for (int d = 0; d < 16; ++d)
      sKV[t][c][d] = (float)(__popcll(k0 & sVm[t][d][0]) + __popcll(k1 & sVm[t][d][1]));
  }
  __syncthreads();

  const int qword = lane >> 4, qsh = (lane & 15) * 2;
  float acc[TT][4][2] = {};
#pragma unroll
  for (int t = 0; t < TT; ++t) {
    for (int c = 0; c < 64; ++c) {
      if (!sQnz[t][c]) continue;
      u32 two = (sQw[t][c][qword] >> qsh) & 3u;
      if (two) {
        float f0 = (float)(two & 1u);
        float f1 = (float)(two >> 1);
        float4 kv = *(const float4*)&sKV[t][c][wave * 4];
        acc[t][0][0] += kv.x * f0; acc[t][0][1] += kv.x * f1;
        acc[t][1][0] += kv.y * f0; acc[t][1][1] += kv.y * f1;
        acc[t][2][0] += kv.z * f0; acc[t][2][1] += kv.z * f1;
        acc[t][3][0] += kv.w * f0; acc[t][3][1] += kv.w * f1;
      }
    }
  }

  // ---- epilogue: LIF(0.5) across t in regs; masks + union activity ----
  float st[4][2] = {};
  u32 actU[4] = {0, 0, 0, 0};
#pragma unroll
  for (int t = 0; t < TT; ++t) {
#pragma unroll
    for (int i = 0; i < 4; ++i) {
      float a0 = acc[t][i][0] * 0.125f, a1 = acc[t][i][1] * 0.125f;
      st[i][0] += (a0 - st[i][0]) * 0.5f;
      st[i][1] += (a1 - st[i][1]) * 0.5f;
      float s0 = (st[i][0] >= 0.5f) ? 1.f : 0.f;
      float s1 = (st[i][1] >= 0.5f) ? 1.f : 0.f;
      st[i][0] *= (1.f - s0); st[i][1] *= (1.f - s1);
      u32 two = ((s0 != 0.f) ? 1u : 0u) | ((s1 != 0.f) ? 2u : 0u);
      u32 wmask = two << qsh;
      wmask |= __shfl_xor(wmask, 1);
      wmask |= __shfl_xor(wmask, 2);
      wmask |= __shfl_xor(wmask, 4);
      wmask |= __shfl_xor(wmask, 8);
      if ((lane & 15) == 0)
        Om[((size_t)b * EE + hh * 64 + dq * 16 + wave * 4 + i) * 16 + qword * 4 + t] = wmask;
      u32 aw = wmask | __shfl_xor(wmask, 16);
      aw |= __shfl_xor(aw, 32);
      actU[i] |= aw;
    }
  }
  if (lane == 0) {
#pragma unroll
    for (int i = 0; i < 4; ++i) sAct[wave * 4 + i] = actU[i] ? 1 : 0;
  }
  __syncthreads();
  if (tid == 0) {
    int slot = hh * 4 + dq;
    int c = 0;
    for (int i = 0; i < 16; ++i)
      if (sAct[i]) idsO[((size_t)b * 32 + slot) * 16 + c++] = (u16)(hh * 64 + dq * 16 + i);
    cntO[(size_t)b * 32 + slot] = c;
  }
}

// ---------------- head: mean over V then LIF over t ----------------
__global__ __launch_bounds__(256) void mean_lif(const float* __restrict__ h,
    float* __restrict__ sh)
{
  int i = blockIdx.x * 256 + threadIdx.x;
  float v = 0.f;
#pragma unroll
  for (int t = 0; t < TT; ++t) {
    const float* p = h + ((size_t)t * BB * EE + i) * VV;
    float s = 0.f;
#pragma unroll
    for (int q = 0; q < VV; q += 4) {
      float4 x = *(const float4*)&p[q];
      s += x.x + x.y + x.z + x.w;
    }
    float hm = s * (1.f / 128.f);
    v += (hm - v) * 0.5f;
    float sp = (v >= 1.f) ? 1.f : 0.f;
    sh[(size_t)t * (BB * EE) + i] = sp;
    v *= (1.f - sp);
  }
}

__global__ __launch_bounds__(256) void head_k2(const float* __restrict__ sh,
    const float* __restrict__ hw, const float* __restrict__ hb,
    float* __restrict__ out)
{
  int g = blockIdx.x * 4 + (threadIdx.x >> 6);
  int lane = threadIdx.x & 63;
  if (g >= BB * 11) return;
  int b = g / 11, n = g % 11;
  float s = 0.f;
#pragma unroll
  for (int t = 0; t < TT; ++t) {
    const float* sp = sh + (size_t)t * (BB * EE) + b * EE;
    const float* wp = hw + n * EE;
    float ss = 0.f;
#pragma unroll
    for (int e = 0; e < EE; e += 64) ss += sp[e + lane] * wp[e + lane];
#pragma unroll
    for (int off = 32; off; off >>= 1) ss += __shfl_down(ss, off);
    if (lane == 0) s += ss;
  }
  if (lane == 0) out[g] = s * 0.25f + hb[n];
}

// ---------------- launch ----------------
extern "C" void kernel_launch(void* const* d_in, const int* in_sizes, int n_in,
                              void* d_out, int out_size, void* d_ws, size_t ws_size,
                              hipStream_t stream) {
  const float* x       = (const float*)d_in[0];
  const float* pe_w    = (const float*)d_in[1];
  const float* pe_bn   = (const float*)d_in[2];
  const float* qkvp_w  = (const float*)d_in[3];
  const float* qkvp_bn = (const float*)d_in[4];
  const float* fc1_w   = (const float*)d_in[5];
  const float* fc1_b   = (const float*)d_in[6];
  const float* fc1_bn  = (const float*)d_in[7];
  const float* fc2_w   = (const float*)d_in[8];
  const float* fc2_b   = (const float*)d_in[9];
  const float* fc2_bn  = (const float*)d_in[10];
  const float* head_w  = (const float*)d_in[11];
  const float* head_b  = (const float*)d_in[12];
  float* out = (float*)d_out;

  const size_t NH = (size_t)TT * BB * EE * VV;       // 4194304
  float* ws = (float*)d_ws;
  float* h   = ws;
  float* wq  = h + NH;
  float* w1  = wq + (size_t)6 * 4 * EE * EE;
  float* w2  = w1 + (size_t)6 * HIDC * EE;
  float* sh  = w2 + (size_t)6 * EE * HIDC;
  // mask buffers: [b][c][q][t] u32 = 16 u32 per (b,c)
  u32* mIn  = (u32*)(sh + (size_t)TT * BB * EE);     // 16*512*16
  u32* mQKV = mIn + (size_t)BB * EE * 16;            // 3x
  u32* mO   = mQKV + (size_t)3 * BB * EE * 16;
  u32* mMlp = mO + (size_t)BB * EE * 16;
  u32* mHid = mMlp + (size_t)BB * EE * 16;           // 16*2048*16
  u32* cntIn = mHid + (size_t)BB * HIDC * 16;        // [16][32]
  u32* cntO  = cntIn + BB * 32;
  u32* cntM  = cntO + BB * 32;
  u32* cntH  = cntM + BB * 32;                       // [16][128]
  u16* idsIn = (u16*)(cntH + BB * 128);              // [16][32][16]
  u16* idsO  = idsIn + (size_t)BB * 32 * 16;
  u16* idsM  = idsO + (size_t)BB * 32 * 16;
  u16* idsH  = idsM + (size_t)BB * 32 * 16;          // [16][128][16]

  u32* mQ = mQKV;
  u32* mK = mQKV + (size_t)BB * EE * 16;
  u32* mV = mQKV + (size_t)2 * BB * EE * 16;

  trans_all<<<dim3(1024, 6, 6), 256, 0, stream>>>(qkvp_w, fc1_w, fc2_w, wq, w1, w2);
  pe_lif<<<dim3(BB, EE / 16), 256, 0, stream>>>(x, pe_w, pe_bn, h, mIn, cntIn, idsIn);

  for (int d = 0; d < 6; ++d) {
    const float* bn1p = qkvp_bn + (size_t)d * 4 * 2 * 4 * EE;
    // qkv (z=3): union lists -> Q/K/V masks (no list emission)
    gemm_fused<<<dim3(BB, EE / 16, 3), 256, 0, stream>>>(mIn, cntIn, idsIn, 32,
        wq + (size_t)d * 4 * EE * EE, nullptr, nullptr, mQ, nullptr, nullptr,
        nullptr, bn1p, bn1p + 4 * EE, EE, EE, 1.f,
        (long)EE * EE, (long)BB * EE * 16, (long)2 * 4 * EE);
    attn_fused<<<dim3(BB, 8, 4), 256, 0, stream>>>(mQ, mK, mV, mO, cntO, idsO);
    // proj: + resid -> h; LIF(1) -> mMlp + union lists
    gemm_fused<<<dim3(BB, EE / 16, 1), 256, 0, stream>>>(mO, cntO, idsO, 32,
        wq + ((size_t)d * 4 + 3) * EE * EE, h, h, mMlp, cntM, idsM,
        nullptr, bn1p + 3 * (2 * 4 * EE), bn1p + 3 * (2 * 4 * EE) + 4 * EE,
        EE, EE, 1.f, 0, 0, 0);
    // fc1: bias+bn; LIF(1) -> mHid + union lists
    gemm_fused<<<dim3(BB, HIDC / 16, 1), 256, 0, stream>>>(mMlp, cntM, idsM, 32,
        w1 + (size_t)d * HIDC * EE, nullptr, nullptr, mHid, cntH, idsH,
        fc1_b + (size_t)d * HIDC, fc1_bn + (size_t)d * 4 * HIDC, nullptr,
        EE, HIDC, 1.f, 0, 0, 0);
    // fc2: bias+bn + resid -> h; LIF(1) -> mIn + union lists (next layer input)
    gemm_fused<<<dim3(BB, EE / 16, 1), 256, 0, stream>>>(mHid, cntH, idsH, 128,
        w2 + (size_t)d * EE * HIDC, h, h, mIn, cntIn, idsIn,
        fc2_b + (size_t)d * EE, fc2_bn + (size_t)d * 4 * EE, nullptr,
        HIDC, EE, 1.f, 0, 0, 0);
  }

  mean_lif<<<32, 256, 0, stream>>>(h, sh);
  head_k2<<<44, 256, 0, stream>>>(sh, head_w, head_b, out);
}